// Round 4
// baseline (299.179 us; speedup 1.0000x reference)
//
#include <hip/hip_runtime.h>

typedef short bf16x8 __attribute__((ext_vector_type(8)));
typedef float floatx4 __attribute__((ext_vector_type(4)));
typedef unsigned short u16;
typedef unsigned int u32;

__device__ __forceinline__ u16 f2bf(float f) {
  u32 u = __float_as_uint(f);
  u += 0x7FFF + ((u >> 16) & 1);   // round-to-nearest-even
  return (u16)(u >> 16);
}
__device__ __forceinline__ u32 packbf(float a, float b) {
  return (u32)f2bf(a) | ((u32)f2bf(b) << 16);
}
// One-instruction RTZ bf16 pair pack: D = {hi16(b), hi16(a)} via v_perm_b32.
__device__ __forceinline__ u32 permpack(u32 a_bits, u32 b_bits) {
  return __builtin_amdgcn_perm(b_bits, a_bits, 0x07060302u);
}

// Raw v_exp_f32: flush-to-zero on underflow (softmax-safe).
__device__ __forceinline__ float ex2(float x) {
#if __has_builtin(__builtin_amdgcn_exp2f)
  return __builtin_amdgcn_exp2f(x);
#else
  float r;
  asm("v_exp_f32 %0, %1" : "=v"(r) : "v"(x));
  return r;
#endif
}

// Async global->LDS DMA, 16 B/lane. LDS dest wave-uniform; lane i lands at
// ldsbase + i*16 (m97/m104 semantics).
__device__ __forceinline__ void gload_lds16(const u16* g, u16* l) {
  __builtin_amdgcn_global_load_lds(
      (const __attribute__((address_space(1))) void*)(const void*)g,
      (__attribute__((address_space(3))) void*)(void*)l, 16, 0, 0);
}

// XCD-aware bijective block swizzle (T1, m204 form; requires nwg % 8 == 0).
__device__ __forceinline__ int xcd_swz(int disp, int nwg) {
  const int q = nwg >> 3;
  return (disp & 7) * q + (disp >> 3);
}

// ===========================================================================
// bf16 GEMM (NT) mainloop, 2-phase pipelined with the stage slot placed
// AFTER the ds_reads (R2's stage-first ordering let conservative alias
// handling insert vmcnt(0) before the reads -> serialization). Here:
//   [sync] ds_read frags(buf cur) | SCHED_BARRIER | issue DMA(t+1 -> other)
//   | SCHED_BARRIER | 16 MFMA | __syncthreads (its vmcnt(0) = per-tile wait)
// A conservative wait before the ds_reads sees zero outstanding vm-ops (the
// previous barrier drained), so it costs nothing; the DMA latency overlaps
// the MFMA block. 128x128 tile, BK=32, 4 waves. K fixed at 1024.
// ===========================================================================
__device__ __forceinline__ void bb_stage(const u16* Ag, const u16* Wg,
                                         u16* Asl, u16* Wsl) {
  gload_lds16(Ag, Asl);
  gload_lds16(Ag + 16 * 1024, Asl + 512);
  gload_lds16(Wg, Wsl);
  gload_lds16(Wg + 16 * 1024, Wsl + 512);
}

__device__ __forceinline__ void bb_frags(const u16* As, const u16* Ws, int wm,
                                         int wn, int m16, int quad,
                                         bf16x8 af[4], bf16x8 bfr[4]) {
#pragma unroll
  for (int t = 0; t < 4; ++t) {
    af[t]  = *(const bf16x8*)&As[(wm * 64 + t * 16 + m16) * 32 + quad * 8];
    bfr[t] = *(const bf16x8*)&Ws[(wn * 64 + t * 16 + m16) * 32 + quad * 8];
  }
}

__device__ __forceinline__ void bb_mfma(const bf16x8 af[4], const bf16x8 bfr[4],
                                        floatx4 acc[4][4]) {
#pragma unroll
  for (int i = 0; i < 4; ++i)
#pragma unroll
    for (int j = 0; j < 4; ++j)
      acc[i][j] = __builtin_amdgcn_mfma_f32_16x16x32_bf16(af[i], bfr[j],
                                                          acc[i][j], 0, 0, 0);
}

__device__ __forceinline__ void bb_mainloop(const u16* __restrict__ A,
                                            const u16* __restrict__ W,
                                            u16* As0, u16* Ws0, u16* As1,
                                            u16* Ws1, int m0, int n0,
                                            floatx4 acc[4][4]) {
  const int tid = threadIdx.x, lane = tid & 63, w = tid >> 6;
  const int wm = w & 1, wn = w >> 1;
  const int m16 = lane & 15, quad = lane >> 4;
  const int lr = lane >> 2;
  const int sc = (lane & 3) * 8;

  const u16* Ag = A + (size_t)(m0 + w * 32 + lr) * 1024 + sc;
  const u16* Wg = W + (size_t)(n0 + w * 32 + lr) * 1024 + sc;
  const int so = (w * 32) * 32;  // wave's staging offset (u16 elements)

#pragma unroll
  for (int i = 0; i < 4; ++i)
#pragma unroll
    for (int j = 0; j < 4; ++j) acc[i][j] = (floatx4)0.0f;

  // prologue: tile 0 -> buf0
  bb_stage(Ag, Wg, As0 + so, Ws0 + so);
  __syncthreads();

  bf16x8 af[4], bfr[4];
  for (int kt = 0; kt < 32; kt += 2) {
    // even tile kt from buf0; prefetch kt+1 -> buf1 AFTER the reads
    bb_frags(As0, Ws0, wm, wn, m16, quad, af, bfr);
    __builtin_amdgcn_sched_barrier(0);
    bb_stage(Ag + (kt + 1) * 32, Wg + (kt + 1) * 32, As1 + so, Ws1 + so);
    __builtin_amdgcn_sched_barrier(0);
    bb_mfma(af, bfr, acc);
    __syncthreads();
    // odd tile kt+1 from buf1; prefetch kt+2 -> buf0 AFTER the reads
    bb_frags(As1, Ws1, wm, wn, m16, quad, af, bfr);
    __builtin_amdgcn_sched_barrier(0);
    if (kt + 2 < 32)
      bb_stage(Ag + (kt + 2) * 32, Wg + (kt + 2) * 32, As0 + so, Ws0 + so);
    __builtin_amdgcn_sched_barrier(0);
    bb_mfma(af, bfr, acc);
    __syncthreads();
  }
}

// ===========================================================================
// Merged Q/K/V projection: 1024 work ids, XCD-swizzled. y<96: Q (scaled by
// 0.125*log2e); [96,112): K; [112,128): V (transposed store
// Vt[b][h*64+d][s]). Branches are block-uniform.
// ===========================================================================
__global__ __launch_bounds__(256) void gemm_qkv(
    const u16* __restrict__ xb, const u16* __restrict__ ctxb,
    const u16* __restrict__ wqb, const u16* __restrict__ wkb,
    const u16* __restrict__ wvb, u16* __restrict__ Qb, u16* __restrict__ Kbuf,
    u16* __restrict__ Vtb) {
  __shared__ u16 As0[128 * 32];
  __shared__ u16 Ws0[128 * 32];
  __shared__ u16 As1[128 * 32];
  __shared__ u16 Ws1[128 * 32];
  const int lane = threadIdx.x & 63, w = threadIdx.x >> 6;
  const int wm = w & 1, wn = w >> 1;
  const int m16 = lane & 15, quad = lane >> 4;
  const int disp = blockIdx.y * 8 + blockIdx.x;
  const int work = xcd_swz(disp, 1024);
  const int y = work >> 3;
  const int n0 = (work & 7) * 128;
  const u16 *A, *W;
  int m0, mode;
  if (y < 96)       { A = xb;   W = wqb; m0 = y * 128;         mode = 0; }
  else if (y < 112) { A = ctxb; W = wkb; m0 = (y - 96) * 128;  mode = 1; }
  else              { A = ctxb; W = wvb; m0 = (y - 112) * 128; mode = 2; }
  floatx4 acc[4][4];
  bb_mainloop(A, W, As0, Ws0, As1, Ws1, m0, n0, acc);
  const float cs = (mode == 0) ? 0.18033688011112042f : 1.0f;
#pragma unroll
  for (int j = 0; j < 4; ++j) {
    const int col = n0 + wn * 64 + j * 16 + m16;
#pragma unroll
    for (int i = 0; i < 4; ++i)
#pragma unroll
      for (int r = 0; r < 4; ++r) {
        const int row = m0 + wm * 64 + i * 16 + quad * 4 + r;
        const u16 v = f2bf(acc[i][j][r] * cs);
        if (mode == 0)
          Qb[(size_t)row * 1024 + col] = v;
        else if (mode == 1)
          Kbuf[(size_t)row * 1024 + col] = v;
        else
          Vtb[((size_t)((row >> 10) * 1024 + col)) * 1024 + (row & 1023)] = v;
      }
  }
}

// Output projection: bf16 A/W -> f32 out + bias. XCD-swizzled (768 blocks).
__global__ __launch_bounds__(256) void gemm_out(const u16* __restrict__ A,
                                                const u16* __restrict__ W,
                                                float* __restrict__ C,
                                                const float* __restrict__ bias) {
  __shared__ u16 As0[128 * 32];
  __shared__ u16 Ws0[128 * 32];
  __shared__ u16 As1[128 * 32];
  __shared__ u16 Ws1[128 * 32];
  const int lane = threadIdx.x & 63, w = threadIdx.x >> 6;
  const int wm = w & 1, wn = w >> 1;
  const int m16 = lane & 15, quad = lane >> 4;
  const int disp = blockIdx.y * 8 + blockIdx.x;
  const int work = xcd_swz(disp, 768);
  const int n0 = (work & 7) * 128, m0 = (work >> 3) * 128;
  floatx4 acc[4][4];
  bb_mainloop(A, W, As0, Ws0, As1, Ws1, m0, n0, acc);
#pragma unroll
  for (int j = 0; j < 4; ++j) {
    const int col = n0 + wn * 64 + j * 16 + m16;
    const float bv = bias[col];
#pragma unroll
    for (int i = 0; i < 4; ++i)
#pragma unroll
      for (int r = 0; r < 4; ++r) {
        const int row = m0 + wm * 64 + i * 16 + quad * 4 + r;
        C[(size_t)row * 1024 + col] = acc[i][j][r] + bv;
      }
  }
}

// ===========================================================================
// f32 -> bf16 conversion of all operands.
// ===========================================================================
__global__ __launch_bounds__(256) void cvt_all(
    const float* __restrict__ x, const float* __restrict__ ctx,
    const float* __restrict__ wq, const float* __restrict__ wk,
    const float* __restrict__ wv, const float* __restrict__ wo,
    u16* __restrict__ xb, u16* __restrict__ ctxb, u16* __restrict__ wqb,
    u16* __restrict__ wkb, u16* __restrict__ wvb, u16* __restrict__ wob) {
  const u32 i = blockIdx.x * 256 + threadIdx.x;
  const float* s;
  u16* d;
  u32 o;
  if (i < 3145728u)      { s = x;   d = xb;   o = i; }
  else if (i < 3670016u) { s = ctx; d = ctxb; o = i - 3145728u; }
  else if (i < 3932160u) { s = wq;  d = wqb;  o = i - 3670016u; }
  else if (i < 4194304u) { s = wk;  d = wkb;  o = i - 3932160u; }
  else if (i < 4456448u) { s = wv;  d = wvb;  o = i - 4194304u; }
  else                   { s = wo;  d = wob;  o = i - 4456448u; }
  const float4 v = ((const float4*)s)[o];
  uint2 p;
  p.x = packbf(v.x, v.y);
  p.y = packbf(v.z, v.w);
  ((uint2*)d)[o] = p;
}

// ===========================================================================
// Flash attention, VALU-trimmed (raw v_exp_f32; MFMA-pipe row-sum), with
// XCD swizzle: each XCD owns 4 contiguous (b,h) pairs -> K/V working set
// 1 MB << 4 MB L2. 64-key tiles, LDS 34.8 KB -> 4 blocks/CU.
// ===========================================================================
__global__ __launch_bounds__(256, 4) void attn_flash(
    const u16* __restrict__ Q, const u16* __restrict__ Kb,
    const u16* __restrict__ Vt, u16* __restrict__ O) {
  __shared__ u16 Kl[2 * 64 * 32];   // [ks][s 64][d 32]
  __shared__ u16 Vl[2 * 64 * 32];   // [sub][d 64][s 32]
  __shared__ u32 Pl[4 * 32 * 36];   // per-wave [q 32][36 dw] (32 payload)
  const int tid = threadIdx.x, lane = tid & 63, w = tid >> 6;
  const int m16 = lane & 15, quad = lane >> 4;
  const int disp =
      blockIdx.x + 48 * (blockIdx.y + 16 * blockIdx.z);  // [0,1536)
  const int work = xcd_swz(disp, 1536);
  const int qx = work % 48;
  const int bh = work / 48;          // [0,32)
  const int h = bh & 15, b = bh >> 4;
  const int q0 = qx * 128 + w * 32;
  u32* const pbase = &Pl[w * 32 * 36];

  // Q fragments (B-operand), already scaled in projection.
  bf16x8 aq[2][2];
#pragma unroll
  for (int qt = 0; qt < 2; ++qt)
#pragma unroll
    for (int ks = 0; ks < 2; ++ks)
      aq[qt][ks] =
          *(const bf16x8*)&Q[((size_t)(b * 6144 + q0 + qt * 16 + m16)) * 1024 +
                             h * 64 + ks * 32 + quad * 8];

  // DMA assignment: wave w -> ks/sub = w&1, row-half = w>>1.
  const int wk = w & 1, wh = w >> 1;
  const u16* kg = Kb + ((size_t)(b * 1024 + wh * 32 + (lane >> 2))) * 1024 +
                  h * 64 + wk * 32 + (lane & 3) * 8;
  const u16* vg = Vt + ((size_t)(b * 16 + h)) * 65536 +
                  (size_t)(wh * 32 + (lane >> 2)) * 1024 + wk * 32 +
                  (lane & 3) * 8;
  u16* const klb = &Kl[wk * 2048 + wh * 1024];
  u16* const vlb = &Vl[wk * 2048 + wh * 1024];

  // All-ones A-operand for the row-sum MFMA.
  bf16x8 vone;
#pragma unroll
  for (int e = 0; e < 8; ++e) vone[e] = (short)0x3F80;

  floatx4 oacc[2][4];
#pragma unroll
  for (int qt = 0; qt < 2; ++qt)
#pragma unroll
    for (int mtd = 0; mtd < 4; ++mtd) oacc[qt][mtd] = (floatx4)0.0f;
  floatx4 lacc[2];
  lacc[0] = (floatx4)0.0f;
  lacc[1] = (floatx4)0.0f;

#pragma unroll 1
  for (int kt = 0; kt < 16; ++kt) {
    // stage K[64s][64d] + Vt[64d][64s] (16 KB total, 4 DMA per wave)
    gload_lds16(kg, klb);
    gload_lds16(kg + 16 * 1024, klb + 512);
    gload_lds16(vg, vlb);
    gload_lds16(vg + 16 * 1024, vlb + 512);
    kg += 64 * 1024;
    vg += 64;
    __syncthreads();

    // Phase A: S^T[s 64][q 32] = K @ Q^T (exp2 domain)
    floatx4 sst[2][4];
#pragma unroll
    for (int mt = 0; mt < 4; ++mt) {
      const int row = mt * 16 + m16;
      const bf16x8 kf0 = *(const bf16x8*)&Kl[row * 32 + quad * 8];
      const bf16x8 kf1 = *(const bf16x8*)&Kl[2048 + row * 32 + quad * 8];
#pragma unroll
      for (int qt = 0; qt < 2; ++qt) {
        floatx4 t = (floatx4)0.0f;
        t = __builtin_amdgcn_mfma_f32_16x16x32_bf16(kf0, aq[qt][0], t, 0, 0, 0);
        sst[qt][mt] =
            __builtin_amdgcn_mfma_f32_16x16x32_bf16(kf1, aq[qt][1], t, 0, 0, 0);
      }
    }
    // Softmax numerators: p = exp2(s), raw v_exp_f32; RTZ-pack via v_perm.
#pragma unroll
    for (int qt = 0; qt < 2; ++qt) {
      u32* const prow = &pbase[(qt * 16 + m16) * 36 + quad * 2];
#pragma unroll
      for (int mt = 0; mt < 4; ++mt) {
        const u32 b0 = __float_as_uint(ex2(sst[qt][mt][0]));
        const u32 b1 = __float_as_uint(ex2(sst[qt][mt][1]));
        const u32 b2 = __float_as_uint(ex2(sst[qt][mt][2]));
        const u32 b3 = __float_as_uint(ex2(sst[qt][mt][3]));
        uint2 pk;
        pk.x = permpack(b0, b1);
        pk.y = permpack(b2, b3);
        *(uint2*)&prow[mt * 8] = pk;
      }
    }
    // Phase B: O^T += Vt @ P^T; ones-MFMA accumulates l = sum_k p.
#pragma unroll
    for (int kk = 0; kk < 2; ++kk) {
      bf16x8 pf[2];
#pragma unroll
      for (int qt = 0; qt < 2; ++qt)
        pf[qt] =
            *(const bf16x8*)&pbase[(qt * 16 + m16) * 36 + kk * 16 + quad * 4];
      lacc[0] = __builtin_amdgcn_mfma_f32_16x16x32_bf16(vone, pf[0], lacc[0],
                                                        0, 0, 0);
      lacc[1] = __builtin_amdgcn_mfma_f32_16x16x32_bf16(vone, pf[1], lacc[1],
                                                        0, 0, 0);
#pragma unroll
      for (int mtd = 0; mtd < 4; ++mtd) {
        const bf16x8 vf =
            *(const bf16x8*)&Vl[kk * 2048 + (mtd * 16 + m16) * 32 + quad * 8];
#pragma unroll
        for (int qt = 0; qt < 2; ++qt)
          oacc[qt][mtd] = __builtin_amdgcn_mfma_f32_16x16x32_bf16(
              vf, pf[qt], oacc[qt][mtd], 0, 0, 0);
      }
    }
    __syncthreads();
  }

#pragma unroll
  for (int qt = 0; qt < 2; ++qt) {
    // lacc rows are identical (ones-A); col = m16 matches this lane's q-row.
    const float linv = 1.0f / lacc[qt][0];
    const size_t obase =
        ((size_t)(b * 6144 + q0 + qt * 16 + m16)) * 1024 + h * 64;
#pragma unroll
    for (int mtd = 0; mtd < 4; ++mtd) {
      const int d0 = mtd * 16 + quad * 4;
      *(u32*)&O[obase + d0] =
          packbf(oacc[qt][mtd][0] * linv, oacc[qt][mtd][1] * linv);
      *(u32*)&O[obase + d0 + 2] =
          packbf(oacc[qt][mtd][2] * linv, oacc[qt][mtd][3] * linv);
    }
  }
}

// ===========================================================================
// Fallback GEMM (f32 operands converted in staging) — only if ws too small.
// ===========================================================================
template <bool A_BF16, bool OUT_F32, int VT, bool BIAS>
__global__ __launch_bounds__(256) void gemm_nt(
    const void* __restrict__ Ap, const float* __restrict__ W,
    void* __restrict__ Cp, const float* __restrict__ bias, int M, int N,
    int K, float scale) {
  __shared__ u16 As[128 * 40];
  __shared__ u16 Ws[128 * 40];
  const int tid = threadIdx.x;
  const int lane = tid & 63;
  const int wv = tid >> 6;
  const int wm = wv & 1, wn = wv >> 1;
  const int m16 = lane & 15, quad = lane >> 4;
  const int n0 = blockIdx.x * 128;
  const int m0 = blockIdx.y * 128;
  const int lr = tid >> 2;
  const int lc = (tid & 3) * 8;
  floatx4 acc[4][4];
#pragma unroll
  for (int i = 0; i < 4; ++i)
#pragma unroll
    for (int j = 0; j < 4; ++j) acc[i][j] = (floatx4)0.0f;
  const int KT = K >> 5;
  for (int kt = 0; kt < KT; ++kt) {
    const int k0 = kt << 5;
#pragma unroll
    for (int j = 0; j < 2; ++j) {
      const int r = lr + 64 * j;
      if (A_BF16) {
        *(uint4*)&As[r * 40 + lc] =
            *(const uint4*)&((const u16*)Ap)[(size_t)(m0 + r) * K + k0 + lc];
      } else {
        const float* Arow = (const float*)Ap + (size_t)(m0 + r) * K + k0 + lc;
        const float4 a0 = *(const float4*)Arow;
        const float4 a1 = *(const float4*)(Arow + 4);
        uint4 p;
        p.x = packbf(a0.x, a0.y); p.y = packbf(a0.z, a0.w);
        p.z = packbf(a1.x, a1.y); p.w = packbf(a1.z, a1.w);
        *(uint4*)&As[r * 40 + lc] = p;
      }
      const float* Wrow = W + (size_t)(n0 + r) * K + k0 + lc;
      const float4 w0 = *(const float4*)Wrow;
      const float4 w1 = *(const float4*)(Wrow + 4);
      uint4 q;
      q.x = packbf(w0.x, w0.y); q.y = packbf(w0.z, w0.w);
      q.z = packbf(w1.x, w1.y); q.w = packbf(w1.z, w1.w);
      *(uint4*)&Ws[r * 40 + lc] = q;
    }
    __syncthreads();
    bf16x8 af[4], bfr[4];
#pragma unroll
    for (int t = 0; t < 4; ++t) {
      af[t]  = *(const bf16x8*)&As[(wm * 64 + t * 16 + m16) * 40 + quad * 8];
      bfr[t] = *(const bf16x8*)&Ws[(wn * 64 + t * 16 + m16) * 40 + quad * 8];
    }
#pragma unroll
    for (int i = 0; i < 4; ++i)
#pragma unroll
      for (int j = 0; j < 4; ++j)
        acc[i][j] = __builtin_amdgcn_mfma_f32_16x16x32_bf16(af[i], bfr[j],
                                                            acc[i][j], 0, 0, 0);
    __syncthreads();
  }
#pragma unroll
  for (int j = 0; j < 4; ++j) {
    const int col = n0 + wn * 64 + j * 16 + m16;
    const float bv = BIAS ? bias[col] : 0.0f;
#pragma unroll
    for (int i = 0; i < 4; ++i)
#pragma unroll
      for (int r = 0; r < 4; ++r) {
        const int row = m0 + wm * 64 + i * 16 + quad * 4 + r;
        const float v = acc[i][j][r] * scale + bv;
        if (OUT_F32)
          ((float*)Cp)[(size_t)row * N + col] = v;
        else if (VT)
          ((u16*)Cp)[((size_t)((row >> 10) * 1024 + col)) * 1024 +
                     (row & 1023)] = f2bf(v);
        else
          ((u16*)Cp)[(size_t)row * N + col] = f2bf(v);
      }
  }
}

// ===========================================================================
extern "C" void kernel_launch(void* const* d_in, const int* in_sizes, int n_in,
                              void* d_out, int out_size, void* d_ws,
                              size_t ws_size, hipStream_t stream) {
  const float* x   = (const float*)d_in[0];
  const float* ctx = (const float*)d_in[1];
  const float* Wq  = (const float*)d_in[2];
  const float* Wk  = (const float*)d_in[3];
  const float* Wv  = (const float*)d_in[4];
  const float* Wo  = (const float*)d_in[5];
  const float* bo  = (const float*)d_in[6];
  float* out = (float*)d_out;
  const dim3 blk(256);
  const float CS = 0.18033688011112042f;  // 0.125 * log2(e)

  // Workspace layout (u16 units)
  u16* Qb   = (u16*)d_ws;            // 12582912
  u16* Kbuf = Qb + 12582912;         // 2097152
  u16* Vtb  = Kbuf + 2097152;        // 2097152
  u16* Obx  = Vtb + 2097152;         // 12582912 (xb before attn, Ob after)
  u16* ctxb = Obx + 12582912;        // 2097152
  u16* wqb  = ctxb + 2097152;        // 1048576
  u16* wkb  = wqb + 1048576;
  u16* wvb  = wkb + 1048576;
  u16* wob  = wvb + 1048576;
  const size_t need = (size_t)(wob + 1048576 - Qb) * sizeof(u16);  // 71.3 MB

  if (ws_size >= need) {
    cvt_all<<<18432, blk, 0, stream>>>(x, ctx, Wq, Wk, Wv, Wo, Obx, ctxb, wqb,
                                       wkb, wvb, wob);
    gemm_qkv<<<dim3(8, 128), blk, 0, stream>>>(Obx, ctxb, wqb, wkb, wvb, Qb,
                                               Kbuf, Vtb);
    attn_flash<<<dim3(48, 16, 2), blk, 0, stream>>>(Qb, Kbuf, Vtb, Obx);
    gemm_out<<<dim3(8, 96), blk, 0, stream>>>(Obx, wob, out, bo);
  } else {
    gemm_nt<false, false, 0, false><<<dim3(8, 96), blk, 0, stream>>>(
        x, Wq, Qb, nullptr, 12288, 1024, 1024, CS);
    gemm_nt<false, false, 0, false><<<dim3(8, 16), blk, 0, stream>>>(
        ctx, Wk, Kbuf, nullptr, 2048, 1024, 1024, 1.0f);
    gemm_nt<false, false, 1, false><<<dim3(8, 16), blk, 0, stream>>>(
        ctx, Wv, Vtb, nullptr, 2048, 1024, 1024, 1.0f);
    attn_flash<<<dim3(48, 16, 2), blk, 0, stream>>>(Qb, Kbuf, Vtb, Obx);
    gemm_nt<true, true, 0, true><<<dim3(8, 96), blk, 0, stream>>>(
        Obx, Wo, out, bo, 12288, 1024, 1024, 1.0f);
  }
}

// Round 5
// 297.809 us; speedup vs baseline: 1.0046x; 1.0046x over previous
//
#include <hip/hip_runtime.h>

typedef short bf16x8 __attribute__((ext_vector_type(8)));
typedef float floatx4 __attribute__((ext_vector_type(4)));
typedef unsigned short u16;
typedef unsigned int u32;

__device__ __forceinline__ u16 f2bf(float f) {
  u32 u = __float_as_uint(f);
  u += 0x7FFF + ((u >> 16) & 1);   // round-to-nearest-even
  return (u16)(u >> 16);
}
__device__ __forceinline__ u32 packbf(float a, float b) {
  return (u32)f2bf(a) | ((u32)f2bf(b) << 16);
}
// One-instruction RTZ bf16 pair pack: D = {hi16(b), hi16(a)} via v_perm_b32.
__device__ __forceinline__ u32 permpack(u32 a_bits, u32 b_bits) {
  return __builtin_amdgcn_perm(b_bits, a_bits, 0x07060302u);
}

// Raw v_exp_f32: flush-to-zero on underflow (softmax-safe).
__device__ __forceinline__ float ex2(float x) {
#if __has_builtin(__builtin_amdgcn_exp2f)
  return __builtin_amdgcn_exp2f(x);
#else
  float r;
  asm("v_exp_f32 %0, %1" : "=v"(r) : "v"(x));
  return r;
#endif
}

// Async global->LDS DMA, 16 B/lane. LDS dest wave-uniform; lane i lands at
// ldsbase + i*16 (m97/m104 semantics).
__device__ __forceinline__ void gload_lds16(const u16* g, u16* l) {
  __builtin_amdgcn_global_load_lds(
      (const __attribute__((address_space(1))) void*)(const void*)g,
      (__attribute__((address_space(3))) void*)(void*)l, 16, 0, 0);
}

// XCD-aware bijective block swizzle (T1, m204 form; requires nwg % 8 == 0).
__device__ __forceinline__ int xcd_swz(int disp, int nwg) {
  const int q = nwg >> 3;
  return (disp & 7) * q + (disp >> 3);
}

// ===========================================================================
// bf16 GEMM (NT) mainloop, 256x256 tile, BK=32, 8 waves (2x4 of 128x64),
// single-buffer 2-barrier (the proven m97 skeleton; both pipelining attempts
// regressed — see R2/R4). Rationale: halves staged bytes per MFMA vs 128^2
// (per-CU per-step 32 KB for 256 MFMAs instead of 64 KB across 4 blocks),
// halving the lockstep DMA-drain that dominates the step at K=1024.
// K fixed at 1024 (32 steps). LDS 32 KB. 1 block/CU (2 waves/SIMD).
// ===========================================================================
__device__ __forceinline__ void bb256_mainloop(const u16* __restrict__ A,
                                               const u16* __restrict__ W,
                                               u16* As, u16* Ws, int m0,
                                               int n0, floatx4 acc[8][4]) {
  const int tid = threadIdx.x, lane = tid & 63, w = tid >> 6;  // w in [0,8)
  const int wm = w & 1, wn = w >> 1;                           // 2 x 4 waves
  const int m16 = lane & 15, quad = lane >> 4;
  const int lr = lane >> 2;        // 0..15 staging row within wave
  const int sc = (lane & 3) * 8;   // staging col (8 bf16 = 16 B)

  // Staging: sweep 0 covers rows [w*16, w*16+16), sweep 1 adds +128.
  const u16* Ag = A + (size_t)(m0 + w * 16 + lr) * 1024 + sc;
  const u16* Wg = W + (size_t)(n0 + w * 16 + lr) * 1024 + sc;
  u16* const Asl = &As[(w * 16) * 32];
  u16* const Wsl = &Ws[(w * 16) * 32];

#pragma unroll
  for (int i = 0; i < 8; ++i)
#pragma unroll
    for (int j = 0; j < 4; ++j) acc[i][j] = (floatx4)0.0f;

  for (int kt = 0; kt < 32; ++kt) {
    gload_lds16(Ag, Asl);
    gload_lds16(Ag + 128 * 1024, Asl + 128 * 32);
    gload_lds16(Wg, Wsl);
    gload_lds16(Wg + 128 * 1024, Wsl + 128 * 32);
    Ag += 32;
    Wg += 32;
    __syncthreads();
    bf16x8 af[8], bfr[4];
#pragma unroll
    for (int t = 0; t < 8; ++t)
      af[t] = *(const bf16x8*)&As[(wm * 128 + t * 16 + m16) * 32 + quad * 8];
#pragma unroll
    for (int j = 0; j < 4; ++j)
      bfr[j] = *(const bf16x8*)&Ws[(wn * 64 + j * 16 + m16) * 32 + quad * 8];
#pragma unroll
    for (int i = 0; i < 8; ++i)
#pragma unroll
      for (int j = 0; j < 4; ++j)
        acc[i][j] = __builtin_amdgcn_mfma_f32_16x16x32_bf16(af[i], bfr[j],
                                                            acc[i][j], 0, 0, 0);
    __syncthreads();
  }
}

// ===========================================================================
// Merged Q/K/V projection: 256 work ids = (y 64) x (x 4), XCD-swizzled
// (exactly 1 block/CU). y<48: Q (scaled by 0.125*log2e); [48,56): K;
// [56,64): V (transposed store Vt[b][h*64+d][s]). Branches block-uniform.
// ===========================================================================
__global__ __launch_bounds__(512, 2) void gemm_qkv(
    const u16* __restrict__ xb, const u16* __restrict__ ctxb,
    const u16* __restrict__ wqb, const u16* __restrict__ wkb,
    const u16* __restrict__ wvb, u16* __restrict__ Qb, u16* __restrict__ Kbuf,
    u16* __restrict__ Vtb) {
  __shared__ u16 As[256 * 32];
  __shared__ u16 Ws[256 * 32];
  const int lane = threadIdx.x & 63, w = threadIdx.x >> 6;
  const int wm = w & 1, wn = w >> 1;
  const int m16 = lane & 15, quad = lane >> 4;
  const int disp = blockIdx.y * 4 + blockIdx.x;
  const int work = xcd_swz(disp, 256);
  const int y = work >> 2;
  const int n0 = (work & 3) * 256;
  const u16 *A, *W;
  int m0, mode;
  if (y < 48)      { A = xb;   W = wqb; m0 = y * 256;        mode = 0; }
  else if (y < 56) { A = ctxb; W = wkb; m0 = (y - 48) * 256; mode = 1; }
  else             { A = ctxb; W = wvb; m0 = (y - 56) * 256; mode = 2; }
  floatx4 acc[8][4];
  bb256_mainloop(A, W, As, Ws, m0, n0, acc);
  const float cs = (mode == 0) ? 0.18033688011112042f : 1.0f;
#pragma unroll
  for (int j = 0; j < 4; ++j) {
    const int col = n0 + wn * 64 + j * 16 + m16;
#pragma unroll
    for (int i = 0; i < 8; ++i)
#pragma unroll
      for (int r = 0; r < 4; ++r) {
        const int row = m0 + wm * 128 + i * 16 + quad * 4 + r;
        const u16 v = f2bf(acc[i][j][r] * cs);
        if (mode == 0)
          Qb[(size_t)row * 1024 + col] = v;
        else if (mode == 1)
          Kbuf[(size_t)row * 1024 + col] = v;
        else
          Vtb[((size_t)((row >> 10) * 1024 + col)) * 1024 + (row & 1023)] = v;
      }
  }
}

// Output projection: bf16 A/W -> f32 out + bias. 192 blocks, XCD-swizzled.
__global__ __launch_bounds__(512, 2) void gemm_out(const u16* __restrict__ A,
                                                   const u16* __restrict__ W,
                                                   float* __restrict__ C,
                                                   const float* __restrict__ bias) {
  __shared__ u16 As[256 * 32];
  __shared__ u16 Ws[256 * 32];
  const int lane = threadIdx.x & 63, w = threadIdx.x >> 6;
  const int wm = w & 1, wn = w >> 1;
  const int m16 = lane & 15, quad = lane >> 4;
  const int disp = blockIdx.y * 4 + blockIdx.x;
  const int work = xcd_swz(disp, 192);
  const int n0 = (work & 3) * 256, m0 = (work >> 2) * 256;
  floatx4 acc[8][4];
  bb256_mainloop(A, W, As, Ws, m0, n0, acc);
#pragma unroll
  for (int j = 0; j < 4; ++j) {
    const int col = n0 + wn * 64 + j * 16 + m16;
    const float bv = bias[col];
#pragma unroll
    for (int i = 0; i < 8; ++i)
#pragma unroll
      for (int r = 0; r < 4; ++r) {
        const int row = m0 + wm * 128 + i * 16 + quad * 4 + r;
        C[(size_t)row * 1024 + col] = acc[i][j][r] + bv;
      }
  }
}

// ===========================================================================
// f32 -> bf16 conversion of all operands.
// ===========================================================================
__global__ __launch_bounds__(256) void cvt_all(
    const float* __restrict__ x, const float* __restrict__ ctx,
    const float* __restrict__ wq, const float* __restrict__ wk,
    const float* __restrict__ wv, const float* __restrict__ wo,
    u16* __restrict__ xb, u16* __restrict__ ctxb, u16* __restrict__ wqb,
    u16* __restrict__ wkb, u16* __restrict__ wvb, u16* __restrict__ wob) {
  const u32 i = blockIdx.x * 256 + threadIdx.x;
  const float* s;
  u16* d;
  u32 o;
  if (i < 3145728u)      { s = x;   d = xb;   o = i; }
  else if (i < 3670016u) { s = ctx; d = ctxb; o = i - 3145728u; }
  else if (i < 3932160u) { s = wq;  d = wqb;  o = i - 3670016u; }
  else if (i < 4194304u) { s = wk;  d = wkb;  o = i - 3932160u; }
  else if (i < 4456448u) { s = wv;  d = wvb;  o = i - 4194304u; }
  else                   { s = wo;  d = wob;  o = i - 4456448u; }
  const float4 v = ((const float4*)s)[o];
  uint2 p;
  p.x = packbf(v.x, v.y);
  p.y = packbf(v.z, v.w);
  ((uint2*)d)[o] = p;
}

// ===========================================================================
// Flash attention, VALU-trimmed (raw v_exp_f32; MFMA-pipe row-sum), with
// XCD swizzle: each XCD owns 4 contiguous (b,h) pairs -> K/V working set
// 1 MB << 4 MB L2. 64-key tiles, LDS 34.8 KB -> 4 blocks/CU.
// ===========================================================================
__global__ __launch_bounds__(256, 4) void attn_flash(
    const u16* __restrict__ Q, const u16* __restrict__ Kb,
    const u16* __restrict__ Vt, u16* __restrict__ O) {
  __shared__ u16 Kl[2 * 64 * 32];   // [ks][s 64][d 32]
  __shared__ u16 Vl[2 * 64 * 32];   // [sub][d 64][s 32]
  __shared__ u32 Pl[4 * 32 * 36];   // per-wave [q 32][36 dw] (32 payload)
  const int tid = threadIdx.x, lane = tid & 63, w = tid >> 6;
  const int m16 = lane & 15, quad = lane >> 4;
  const int disp =
      blockIdx.x + 48 * (blockIdx.y + 16 * blockIdx.z);  // [0,1536)
  const int work = xcd_swz(disp, 1536);
  const int qx = work % 48;
  const int bh = work / 48;          // [0,32)
  const int h = bh & 15, b = bh >> 4;
  const int q0 = qx * 128 + w * 32;
  u32* const pbase = &Pl[w * 32 * 36];

  // Q fragments (B-operand), already scaled in projection.
  bf16x8 aq[2][2];
#pragma unroll
  for (int qt = 0; qt < 2; ++qt)
#pragma unroll
    for (int ks = 0; ks < 2; ++ks)
      aq[qt][ks] =
          *(const bf16x8*)&Q[((size_t)(b * 6144 + q0 + qt * 16 + m16)) * 1024 +
                             h * 64 + ks * 32 + quad * 8];

  // DMA assignment: wave w -> ks/sub = w&1, row-half = w>>1.
  const int wk = w & 1, wh = w >> 1;
  const u16* kg = Kb + ((size_t)(b * 1024 + wh * 32 + (lane >> 2))) * 1024 +
                  h * 64 + wk * 32 + (lane & 3) * 8;
  const u16* vg = Vt + ((size_t)(b * 16 + h)) * 65536 +
                  (size_t)(wh * 32 + (lane >> 2)) * 1024 + wk * 32 +
                  (lane & 3) * 8;
  u16* const klb = &Kl[wk * 2048 + wh * 1024];
  u16* const vlb = &Vl[wk * 2048 + wh * 1024];

  // All-ones A-operand for the row-sum MFMA.
  bf16x8 vone;
#pragma unroll
  for (int e = 0; e < 8; ++e) vone[e] = (short)0x3F80;

  floatx4 oacc[2][4];
#pragma unroll
  for (int qt = 0; qt < 2; ++qt)
#pragma unroll
    for (int mtd = 0; mtd < 4; ++mtd) oacc[qt][mtd] = (floatx4)0.0f;
  floatx4 lacc[2];
  lacc[0] = (floatx4)0.0f;
  lacc[1] = (floatx4)0.0f;

#pragma unroll 1
  for (int kt = 0; kt < 16; ++kt) {
    // stage K[64s][64d] + Vt[64d][64s] (16 KB total, 4 DMA per wave)
    gload_lds16(kg, klb);
    gload_lds16(kg + 16 * 1024, klb + 512);
    gload_lds16(vg, vlb);
    gload_lds16(vg + 16 * 1024, vlb + 512);
    kg += 64 * 1024;
    vg += 64;
    __syncthreads();

    // Phase A: S^T[s 64][q 32] = K @ Q^T (exp2 domain)
    floatx4 sst[2][4];
#pragma unroll
    for (int mt = 0; mt < 4; ++mt) {
      const int row = mt * 16 + m16;
      const bf16x8 kf0 = *(const bf16x8*)&Kl[row * 32 + quad * 8];
      const bf16x8 kf1 = *(const bf16x8*)&Kl[2048 + row * 32 + quad * 8];
#pragma unroll
      for (int qt = 0; qt < 2; ++qt) {
        floatx4 t = (floatx4)0.0f;
        t = __builtin_amdgcn_mfma_f32_16x16x32_bf16(kf0, aq[qt][0], t, 0, 0, 0);
        sst[qt][mt] =
            __builtin_amdgcn_mfma_f32_16x16x32_bf16(kf1, aq[qt][1], t, 0, 0, 0);
      }
    }
    // Softmax numerators: p = exp2(s), raw v_exp_f32; RTZ-pack via v_perm.
#pragma unroll
    for (int qt = 0; qt < 2; ++qt) {
      u32* const prow = &pbase[(qt * 16 + m16) * 36 + quad * 2];
#pragma unroll
      for (int mt = 0; mt < 4; ++mt) {
        const u32 b0 = __float_as_uint(ex2(sst[qt][mt][0]));
        const u32 b1 = __float_as_uint(ex2(sst[qt][mt][1]));
        const u32 b2 = __float_as_uint(ex2(sst[qt][mt][2]));
        const u32 b3 = __float_as_uint(ex2(sst[qt][mt][3]));
        uint2 pk;
        pk.x = permpack(b0, b1);
        pk.y = permpack(b2, b3);
        *(uint2*)&prow[mt * 8] = pk;
      }
    }
    // Phase B: O^T += Vt @ P^T; ones-MFMA accumulates l = sum_k p.
#pragma unroll
    for (int kk = 0; kk < 2; ++kk) {
      bf16x8 pf[2];
#pragma unroll
      for (int qt = 0; qt < 2; ++qt)
        pf[qt] =
            *(const bf16x8*)&pbase[(qt * 16 + m16) * 36 + kk * 16 + quad * 4];
      lacc[0] = __builtin_amdgcn_mfma_f32_16x16x32_bf16(vone, pf[0], lacc[0],
                                                        0, 0, 0);
      lacc[1] = __builtin_amdgcn_mfma_f32_16x16x32_bf16(vone, pf[1], lacc[1],
                                                        0, 0, 0);
#pragma unroll
      for (int mtd = 0; mtd < 4; ++mtd) {
        const bf16x8 vf =
            *(const bf16x8*)&Vl[kk * 2048 + (mtd * 16 + m16) * 32 + quad * 8];
#pragma unroll
        for (int qt = 0; qt < 2; ++qt)
          oacc[qt][mtd] = __builtin_amdgcn_mfma_f32_16x16x32_bf16(
              vf, pf[qt], oacc[qt][mtd], 0, 0, 0);
      }
    }
    __syncthreads();
  }

#pragma unroll
  for (int qt = 0; qt < 2; ++qt) {
    // lacc rows are identical (ones-A); col = m16 matches this lane's q-row.
    const float linv = 1.0f / lacc[qt][0];
    const size_t obase =
        ((size_t)(b * 6144 + q0 + qt * 16 + m16)) * 1024 + h * 64;
#pragma unroll
    for (int mtd = 0; mtd < 4; ++mtd) {
      const int d0 = mtd * 16 + quad * 4;
      *(u32*)&O[obase + d0] =
          packbf(oacc[qt][mtd][0] * linv, oacc[qt][mtd][1] * linv);
      *(u32*)&O[obase + d0 + 2] =
          packbf(oacc[qt][mtd][2] * linv, oacc[qt][mtd][3] * linv);
    }
  }
}

// ===========================================================================
// Fallback GEMM (f32 operands converted in staging) — only if ws too small.
// ===========================================================================
template <bool A_BF16, bool OUT_F32, int VT, bool BIAS>
__global__ __launch_bounds__(256) void gemm_nt(
    const void* __restrict__ Ap, const float* __restrict__ W,
    void* __restrict__ Cp, const float* __restrict__ bias, int M, int N,
    int K, float scale) {
  __shared__ u16 As[128 * 40];
  __shared__ u16 Ws[128 * 40];
  const int tid = threadIdx.x;
  const int lane = tid & 63;
  const int wv = tid >> 6;
  const int wm = wv & 1, wn = wv >> 1;
  const int m16 = lane & 15, quad = lane >> 4;
  const int n0 = blockIdx.x * 128;
  const int m0 = blockIdx.y * 128;
  const int lr = tid >> 2;
  const int lc = (tid & 3) * 8;
  floatx4 acc[4][4];
#pragma unroll
  for (int i = 0; i < 4; ++i)
#pragma unroll
    for (int j = 0; j < 4; ++j) acc[i][j] = (floatx4)0.0f;
  const int KT = K >> 5;
  for (int kt = 0; kt < KT; ++kt) {
    const int k0 = kt << 5;
#pragma unroll
    for (int j = 0; j < 2; ++j) {
      const int r = lr + 64 * j;
      if (A_BF16) {
        *(uint4*)&As[r * 40 + lc] =
            *(const uint4*)&((const u16*)Ap)[(size_t)(m0 + r) * K + k0 + lc];
      } else {
        const float* Arow = (const float*)Ap + (size_t)(m0 + r) * K + k0 + lc;
        const float4 a0 = *(const float4*)Arow;
        const float4 a1 = *(const float4*)(Arow + 4);
        uint4 p;
        p.x = packbf(a0.x, a0.y); p.y = packbf(a0.z, a0.w);
        p.z = packbf(a1.x, a1.y); p.w = packbf(a1.z, a1.w);
        *(uint4*)&As[r * 40 + lc] = p;
      }
      const float* Wrow = W + (size_t)(n0 + r) * K + k0 + lc;
      const float4 w0 = *(const float4*)Wrow;
      const float4 w1 = *(const float4*)(Wrow + 4);
      uint4 q;
      q.x = packbf(w0.x, w0.y); q.y = packbf(w0.z, w0.w);
      q.z = packbf(w1.x, w1.y); q.w = packbf(w1.z, w1.w);
      *(uint4*)&Ws[r * 40 + lc] = q;
    }
    __syncthreads();
    bf16x8 af[4], bfr[4];
#pragma unroll
    for (int t = 0; t < 4; ++t) {
      af[t]  = *(const bf16x8*)&As[(wm * 64 + t * 16 + m16) * 40 + quad * 8];
      bfr[t] = *(const bf16x8*)&Ws[(wn * 64 + t * 16 + m16) * 40 + quad * 8];
    }
#pragma unroll
    for (int i = 0; i < 4; ++i)
#pragma unroll
      for (int j = 0; j < 4; ++j)
        acc[i][j] = __builtin_amdgcn_mfma_f32_16x16x32_bf16(af[i], bfr[j],
                                                            acc[i][j], 0, 0, 0);
    __syncthreads();
  }
#pragma unroll
  for (int j = 0; j < 4; ++j) {
    const int col = n0 + wn * 64 + j * 16 + m16;
    const float bv = BIAS ? bias[col] : 0.0f;
#pragma unroll
    for (int i = 0; i < 4; ++i)
#pragma unroll
      for (int r = 0; r < 4; ++r) {
        const int row = m0 + wm * 64 + i * 16 + quad * 4 + r;
        const float v = acc[i][j][r] * scale + bv;
        if (OUT_F32)
          ((float*)Cp)[(size_t)row * N + col] = v;
        else if (VT)
          ((u16*)Cp)[((size_t)((row >> 10) * 1024 + col)) * 1024 +
                     (row & 1023)] = f2bf(v);
        else
          ((u16*)Cp)[(size_t)row * N + col] = f2bf(v);
      }
  }
}

// ===========================================================================
extern "C" void kernel_launch(void* const* d_in, const int* in_sizes, int n_in,
                              void* d_out, int out_size, void* d_ws,
                              size_t ws_size, hipStream_t stream) {
  const float* x   = (const float*)d_in[0];
  const float* ctx = (const float*)d_in[1];
  const float* Wq  = (const float*)d_in[2];
  const float* Wk  = (const float*)d_in[3];
  const float* Wv  = (const float*)d_in[4];
  const float* Wo  = (const float*)d_in[5];
  const float* bo  = (const float*)d_in[6];
  float* out = (float*)d_out;
  const dim3 blk(256);
  const dim3 blk512(512);
  const float CS = 0.18033688011112042f;  // 0.125 * log2(e)

  // Workspace layout (u16 units)
  u16* Qb   = (u16*)d_ws;            // 12582912
  u16* Kbuf = Qb + 12582912;         // 2097152
  u16* Vtb  = Kbuf + 2097152;        // 2097152
  u16* Obx  = Vtb + 2097152;         // 12582912 (xb before attn, Ob after)
  u16* ctxb = Obx + 12582912;        // 2097152
  u16* wqb  = ctxb + 2097152;        // 1048576
  u16* wkb  = wqb + 1048576;
  u16* wvb  = wkb + 1048576;
  u16* wob  = wvb + 1048576;
  const size_t need = (size_t)(wob + 1048576 - Qb) * sizeof(u16);  // 71.3 MB

  if (ws_size >= need) {
    cvt_all<<<18432, blk, 0, stream>>>(x, ctx, Wq, Wk, Wv, Wo, Obx, ctxb, wqb,
                                       wkb, wvb, wob);
    gemm_qkv<<<dim3(4, 64), blk512, 0, stream>>>(Obx, ctxb, wqb, wkb, wvb, Qb,
                                                 Kbuf, Vtb);
    attn_flash<<<dim3(48, 16, 2), blk, 0, stream>>>(Qb, Kbuf, Vtb, Obx);
    gemm_out<<<dim3(4, 48), blk512, 0, stream>>>(Obx, wob, out, bo);
  } else {
    gemm_nt<false, false, 0, false><<<dim3(8, 96), blk, 0, stream>>>(
        x, Wq, Qb, nullptr, 12288, 1024, 1024, CS);
    gemm_nt<false, false, 0, false><<<dim3(8, 16), blk, 0, stream>>>(
        ctx, Wk, Kbuf, nullptr, 2048, 1024, 1024, 1.0f);
    gemm_nt<false, false, 1, false><<<dim3(8, 16), blk, 0, stream>>>(
        ctx, Wv, Vtb, nullptr, 2048, 1024, 1024, 1.0f);
    attn_flash<<<dim3(48, 16, 2), blk, 0, stream>>>(Qb, Kbuf, Vtb, Obx);
    gemm_nt<true, true, 0, true><<<dim3(8, 96), blk, 0, stream>>>(
        Obx, Wo, out, bo, 12288, 1024, 1024, 1.0f);
  }
}

// Round 6
// 288.620 us; speedup vs baseline: 1.0366x; 1.0318x over previous
//
#include <hip/hip_runtime.h>

typedef short bf16x8 __attribute__((ext_vector_type(8)));
typedef float floatx4 __attribute__((ext_vector_type(4)));
typedef unsigned short u16;
typedef unsigned int u32;

__device__ __forceinline__ u16 f2bf(float f) {
  u32 u = __float_as_uint(f);
  u += 0x7FFF + ((u >> 16) & 1);   // round-to-nearest-even
  return (u16)(u >> 16);
}
__device__ __forceinline__ u32 packbf(float a, float b) {
  return (u32)f2bf(a) | ((u32)f2bf(b) << 16);
}
// One-instruction RTZ bf16 pair pack: D = {hi16(b), hi16(a)} via v_perm_b32.
__device__ __forceinline__ u32 permpack(u32 a_bits, u32 b_bits) {
  return __builtin_amdgcn_perm(b_bits, a_bits, 0x07060302u);
}

// Raw v_exp_f32: flush-to-zero on underflow (softmax-safe).
__device__ __forceinline__ float ex2(float x) {
#if __has_builtin(__builtin_amdgcn_exp2f)
  return __builtin_amdgcn_exp2f(x);
#else
  float r;
  asm("v_exp_f32 %0, %1" : "=v"(r) : "v"(x));
  return r;
#endif
}

// Async global->LDS DMA, 16 B/lane. LDS dest wave-uniform; lane i lands at
// ldsbase + i*16 (m97/m104 semantics).
__device__ __forceinline__ void gload_lds16(const u16* g, u16* l) {
  __builtin_amdgcn_global_load_lds(
      (const __attribute__((address_space(1))) void*)(const void*)g,
      (__attribute__((address_space(3))) void*)(void*)l, 16, 0, 0);
}

// XCD-aware bijective block swizzle (T1, m204 form; requires nwg % 8 == 0).
__device__ __forceinline__ int xcd_swz(int disp, int nwg) {
  const int q = nwg >> 3;
  return (disp & 7) * q + (disp >> 3);
}

// ===========================================================================
// Shared GEMM building blocks: 128x128 tile, BK=32, 4 waves (2x2 of 64x64).
// ===========================================================================
__device__ __forceinline__ void bb_stage(const u16* Ag, const u16* Wg,
                                         u16* Asl, u16* Wsl) {
  gload_lds16(Ag, Asl);
  gload_lds16(Ag + 16 * 1024, Asl + 512);
  gload_lds16(Wg, Wsl);
  gload_lds16(Wg + 16 * 1024, Wsl + 512);
}

__device__ __forceinline__ void bb_frags(const u16* As, const u16* Ws, int wm,
                                         int wn, int m16, int quad,
                                         bf16x8 af[4], bf16x8 bfr[4]) {
#pragma unroll
  for (int t = 0; t < 4; ++t) {
    af[t]  = *(const bf16x8*)&As[(wm * 64 + t * 16 + m16) * 32 + quad * 8];
    bfr[t] = *(const bf16x8*)&Ws[(wn * 64 + t * 16 + m16) * 32 + quad * 8];
  }
}

__device__ __forceinline__ void bb_mfma(const bf16x8 af[4], const bf16x8 bfr[4],
                                        floatx4 acc[4][4]) {
#pragma unroll
  for (int i = 0; i < 4; ++i)
#pragma unroll
    for (int j = 0; j < 4; ++j)
      acc[i][j] = __builtin_amdgcn_mfma_f32_16x16x32_bf16(af[i], bfr[j],
                                                          acc[i][j], 0, 0, 0);
}

// Single-buffer 2-barrier mainloop (proven R3 baseline; used by gemm_out).
__device__ __forceinline__ void bb_mainloop(const u16* __restrict__ A,
                                            const u16* __restrict__ W,
                                            u16* As, u16* Ws, int m0, int n0,
                                            floatx4 acc[4][4]) {
  const int tid = threadIdx.x, lane = tid & 63, w = tid >> 6;
  const int wm = w & 1, wn = w >> 1;
  const int m16 = lane & 15, quad = lane >> 4;
  const int lr = lane >> 2;
  const int sc = (lane & 3) * 8;

  const u16* Ag = A + (size_t)(m0 + w * 32 + lr) * 1024 + sc;
  const u16* Wg = W + (size_t)(n0 + w * 32 + lr) * 1024 + sc;
  u16* const Asl = &As[(w * 32) * 32];
  u16* const Wsl = &Ws[(w * 32) * 32];

#pragma unroll
  for (int i = 0; i < 4; ++i)
#pragma unroll
    for (int j = 0; j < 4; ++j) acc[i][j] = (floatx4)0.0f;

  for (int kt = 0; kt < 32; ++kt) {
    bb_stage(Ag, Wg, Asl, Wsl);
    Ag += 32;
    Wg += 32;
    __syncthreads();
    bf16x8 af[4], bfr[4];
    bb_frags(As, Ws, wm, wn, m16, quad, af, bfr);
    bb_mfma(af, bfr, acc);
    __syncthreads();
  }
}

// T3-minimum 2-phase pipelined mainloop with RAW s_barrier + inline-asm
// vmcnt (no __syncthreads in the loop -> no compiler-forced full drain
// before the ds_reads; R2/R4's failure mode). Per K-step: issue next-tile
// DMAs into the other buffer, ds_read+MFMA current, THEN vmcnt(0)+barrier.
// DMA latency overlaps the compute phase. Race-freedom: each wave's
// ds_reads of buf X are lgkm-complete before its MFMAs, hence before its
// barrier arrival; the stage into X is issued only after that barrier (WAR
// safe). DMA writes are vmcnt-drained before the barrier preceding their
// readers (RAW safe). Used by gemm_qkv (A/B vs gemm_out's baseline loop).
__device__ __forceinline__ void bb_mainloop_pipe(const u16* __restrict__ A,
                                                 const u16* __restrict__ W,
                                                 u16* As0, u16* Ws0, u16* As1,
                                                 u16* Ws1, int m0, int n0,
                                                 floatx4 acc[4][4]) {
  const int tid = threadIdx.x, lane = tid & 63, w = tid >> 6;
  const int wm = w & 1, wn = w >> 1;
  const int m16 = lane & 15, quad = lane >> 4;
  const int lr = lane >> 2;
  const int sc = (lane & 3) * 8;

  const u16* Ag = A + (size_t)(m0 + w * 32 + lr) * 1024 + sc;
  const u16* Wg = W + (size_t)(n0 + w * 32 + lr) * 1024 + sc;
  const int so = (w * 32) * 32;  // wave's staging offset (u16 elements)

#pragma unroll
  for (int i = 0; i < 4; ++i)
#pragma unroll
    for (int j = 0; j < 4; ++j) acc[i][j] = (floatx4)0.0f;

  // prologue: tile 0 -> buf0, drain, sync
  bb_stage(Ag, Wg, As0 + so, Ws0 + so);
  asm volatile("s_waitcnt vmcnt(0)" ::: "memory");
  __builtin_amdgcn_s_barrier();

  bf16x8 af[4], bfr[4];
  for (int kt = 0; kt < 32; kt += 2) {
    // phase 0: stage kt+1 -> buf1; compute tile kt from buf0
    bb_stage(Ag + (kt + 1) * 32, Wg + (kt + 1) * 32, As1 + so, Ws1 + so);
    bb_frags(As0, Ws0, wm, wn, m16, quad, af, bfr);
    bb_mfma(af, bfr, acc);
    asm volatile("s_waitcnt vmcnt(0)" ::: "memory");
    __builtin_amdgcn_s_barrier();
    // phase 1: stage kt+2 -> buf0; compute tile kt+1 from buf1
    if (kt + 2 < 32)
      bb_stage(Ag + (kt + 2) * 32, Wg + (kt + 2) * 32, As0 + so, Ws0 + so);
    bb_frags(As1, Ws1, wm, wn, m16, quad, af, bfr);
    bb_mfma(af, bfr, acc);
    asm volatile("s_waitcnt vmcnt(0)" ::: "memory");
    __builtin_amdgcn_s_barrier();
  }
}

// ===========================================================================
// Merged Q/K/V projection: 1024 work ids, XCD-swizzled. y<96: Q (scaled by
// 0.125*log2e); [96,112): K; [112,128): V (transposed store
// Vt[b][h*64+d][s]). Branches are block-uniform. PIPELINED mainloop.
// ===========================================================================
__global__ __launch_bounds__(256) void gemm_qkv(
    const u16* __restrict__ xb, const u16* __restrict__ ctxb,
    const u16* __restrict__ wqb, const u16* __restrict__ wkb,
    const u16* __restrict__ wvb, u16* __restrict__ Qb, u16* __restrict__ Kbuf,
    u16* __restrict__ Vtb) {
  __shared__ u16 As0[128 * 32];
  __shared__ u16 Ws0[128 * 32];
  __shared__ u16 As1[128 * 32];
  __shared__ u16 Ws1[128 * 32];
  const int lane = threadIdx.x & 63, w = threadIdx.x >> 6;
  const int wm = w & 1, wn = w >> 1;
  const int m16 = lane & 15, quad = lane >> 4;
  const int disp = blockIdx.y * 8 + blockIdx.x;
  const int work = xcd_swz(disp, 1024);
  const int y = work >> 3;
  const int n0 = (work & 7) * 128;
  const u16 *A, *W;
  int m0, mode;
  if (y < 96)       { A = xb;   W = wqb; m0 = y * 128;         mode = 0; }
  else if (y < 112) { A = ctxb; W = wkb; m0 = (y - 96) * 128;  mode = 1; }
  else              { A = ctxb; W = wvb; m0 = (y - 112) * 128; mode = 2; }
  floatx4 acc[4][4];
  bb_mainloop_pipe(A, W, As0, Ws0, As1, Ws1, m0, n0, acc);
  const float cs = (mode == 0) ? 0.18033688011112042f : 1.0f;
#pragma unroll
  for (int j = 0; j < 4; ++j) {
    const int col = n0 + wn * 64 + j * 16 + m16;
#pragma unroll
    for (int i = 0; i < 4; ++i)
#pragma unroll
      for (int r = 0; r < 4; ++r) {
        const int row = m0 + wm * 64 + i * 16 + quad * 4 + r;
        const u16 v = f2bf(acc[i][j][r] * cs);
        if (mode == 0)
          Qb[(size_t)row * 1024 + col] = v;
        else if (mode == 1)
          Kbuf[(size_t)row * 1024 + col] = v;
        else
          Vtb[((size_t)((row >> 10) * 1024 + col)) * 1024 + (row & 1023)] = v;
      }
  }
}

// Output projection: bf16 A/W -> f32 out + bias. XCD-swizzled (768 blocks).
// Baseline single-buffer mainloop (control arm of the A/B).
__global__ __launch_bounds__(256) void gemm_out(const u16* __restrict__ A,
                                                const u16* __restrict__ W,
                                                float* __restrict__ C,
                                                const float* __restrict__ bias) {
  __shared__ u16 As[128 * 32];
  __shared__ u16 Ws[128 * 32];
  const int lane = threadIdx.x & 63, w = threadIdx.x >> 6;
  const int wm = w & 1, wn = w >> 1;
  const int m16 = lane & 15, quad = lane >> 4;
  const int disp = blockIdx.y * 8 + blockIdx.x;
  const int work = xcd_swz(disp, 768);
  const int n0 = (work & 7) * 128, m0 = (work >> 3) * 128;
  floatx4 acc[4][4];
  bb_mainloop(A, W, As, Ws, m0, n0, acc);
#pragma unroll
  for (int j = 0; j < 4; ++j) {
    const int col = n0 + wn * 64 + j * 16 + m16;
    const float bv = bias[col];
#pragma unroll
    for (int i = 0; i < 4; ++i)
#pragma unroll
      for (int r = 0; r < 4; ++r) {
        const int row = m0 + wm * 64 + i * 16 + quad * 4 + r;
        C[(size_t)row * 1024 + col] = acc[i][j][r] + bv;
      }
  }
}

// ===========================================================================
// f32 -> bf16 conversion of all operands.
// ===========================================================================
__global__ __launch_bounds__(256) void cvt_all(
    const float* __restrict__ x, const float* __restrict__ ctx,
    const float* __restrict__ wq, const float* __restrict__ wk,
    const float* __restrict__ wv, const float* __restrict__ wo,
    u16* __restrict__ xb, u16* __restrict__ ctxb, u16* __restrict__ wqb,
    u16* __restrict__ wkb, u16* __restrict__ wvb, u16* __restrict__ wob) {
  const u32 i = blockIdx.x * 256 + threadIdx.x;
  const float* s;
  u16* d;
  u32 o;
  if (i < 3145728u)      { s = x;   d = xb;   o = i; }
  else if (i < 3670016u) { s = ctx; d = ctxb; o = i - 3145728u; }
  else if (i < 3932160u) { s = wq;  d = wqb;  o = i - 3670016u; }
  else if (i < 4194304u) { s = wk;  d = wkb;  o = i - 3932160u; }
  else if (i < 4456448u) { s = wv;  d = wvb;  o = i - 4194304u; }
  else                   { s = wo;  d = wob;  o = i - 4456448u; }
  const float4 v = ((const float4*)s)[o];
  uint2 p;
  p.x = packbf(v.x, v.y);
  p.y = packbf(v.z, v.w);
  ((uint2*)d)[o] = p;
}

// ===========================================================================
// Flash attention, VALU-trimmed (raw v_exp_f32; MFMA-pipe row-sum), with
// XCD swizzle: each XCD owns 4 contiguous (b,h) pairs -> K/V working set
// 1 MB << 4 MB L2. 64-key tiles, LDS 34.8 KB -> 4 blocks/CU.
// ===========================================================================
__global__ __launch_bounds__(256, 4) void attn_flash(
    const u16* __restrict__ Q, const u16* __restrict__ Kb,
    const u16* __restrict__ Vt, u16* __restrict__ O) {
  __shared__ u16 Kl[2 * 64 * 32];   // [ks][s 64][d 32]
  __shared__ u16 Vl[2 * 64 * 32];   // [sub][d 64][s 32]
  __shared__ u32 Pl[4 * 32 * 36];   // per-wave [q 32][36 dw] (32 payload)
  const int tid = threadIdx.x, lane = tid & 63, w = tid >> 6;
  const int m16 = lane & 15, quad = lane >> 4;
  const int disp =
      blockIdx.x + 48 * (blockIdx.y + 16 * blockIdx.z);  // [0,1536)
  const int work = xcd_swz(disp, 1536);
  const int qx = work % 48;
  const int bh = work / 48;          // [0,32)
  const int h = bh & 15, b = bh >> 4;
  const int q0 = qx * 128 + w * 32;
  u32* const pbase = &Pl[w * 32 * 36];

  // Q fragments (B-operand), already scaled in projection.
  bf16x8 aq[2][2];
#pragma unroll
  for (int qt = 0; qt < 2; ++qt)
#pragma unroll
    for (int ks = 0; ks < 2; ++ks)
      aq[qt][ks] =
          *(const bf16x8*)&Q[((size_t)(b * 6144 + q0 + qt * 16 + m16)) * 1024 +
                             h * 64 + ks * 32 + quad * 8];

  // DMA assignment: wave w -> ks/sub = w&1, row-half = w>>1.
  const int wk = w & 1, wh = w >> 1;
  const u16* kg = Kb + ((size_t)(b * 1024 + wh * 32 + (lane >> 2))) * 1024 +
                  h * 64 + wk * 32 + (lane & 3) * 8;
  const u16* vg = Vt + ((size_t)(b * 16 + h)) * 65536 +
                  (size_t)(wh * 32 + (lane >> 2)) * 1024 + wk * 32 +
                  (lane & 3) * 8;
  u16* const klb = &Kl[wk * 2048 + wh * 1024];
  u16* const vlb = &Vl[wk * 2048 + wh * 1024];

  // All-ones A-operand for the row-sum MFMA.
  bf16x8 vone;
#pragma unroll
  for (int e = 0; e < 8; ++e) vone[e] = (short)0x3F80;

  floatx4 oacc[2][4];
#pragma unroll
  for (int qt = 0; qt < 2; ++qt)
#pragma unroll
    for (int mtd = 0; mtd < 4; ++mtd) oacc[qt][mtd] = (floatx4)0.0f;
  floatx4 lacc[2];
  lacc[0] = (floatx4)0.0f;
  lacc[1] = (floatx4)0.0f;

#pragma unroll 1
  for (int kt = 0; kt < 16; ++kt) {
    // stage K[64s][64d] + Vt[64d][64s] (16 KB total, 4 DMA per wave)
    gload_lds16(kg, klb);
    gload_lds16(kg + 16 * 1024, klb + 512);
    gload_lds16(vg, vlb);
    gload_lds16(vg + 16 * 1024, vlb + 512);
    kg += 64 * 1024;
    vg += 64;
    __syncthreads();

    // Phase A: S^T[s 64][q 32] = K @ Q^T (exp2 domain)
    floatx4 sst[2][4];
#pragma unroll
    for (int mt = 0; mt < 4; ++mt) {
      const int row = mt * 16 + m16;
      const bf16x8 kf0 = *(const bf16x8*)&Kl[row * 32 + quad * 8];
      const bf16x8 kf1 = *(const bf16x8*)&Kl[2048 + row * 32 + quad * 8];
#pragma unroll
      for (int qt = 0; qt < 2; ++qt) {
        floatx4 t = (floatx4)0.0f;
        t = __builtin_amdgcn_mfma_f32_16x16x32_bf16(kf0, aq[qt][0], t, 0, 0, 0);
        sst[qt][mt] =
            __builtin_amdgcn_mfma_f32_16x16x32_bf16(kf1, aq[qt][1], t, 0, 0, 0);
      }
    }
    // Softmax numerators: p = exp2(s), raw v_exp_f32; RTZ-pack via v_perm.
#pragma unroll
    for (int qt = 0; qt < 2; ++qt) {
      u32* const prow = &pbase[(qt * 16 + m16) * 36 + quad * 2];
#pragma unroll
      for (int mt = 0; mt < 4; ++mt) {
        const u32 b0 = __float_as_uint(ex2(sst[qt][mt][0]));
        const u32 b1 = __float_as_uint(ex2(sst[qt][mt][1]));
        const u32 b2 = __float_as_uint(ex2(sst[qt][mt][2]));
        const u32 b3 = __float_as_uint(ex2(sst[qt][mt][3]));
        uint2 pk;
        pk.x = permpack(b0, b1);
        pk.y = permpack(b2, b3);
        *(uint2*)&prow[mt * 8] = pk;
      }
    }
    // Phase B: O^T += Vt @ P^T; ones-MFMA accumulates l = sum_k p.
#pragma unroll
    for (int kk = 0; kk < 2; ++kk) {
      bf16x8 pf[2];
#pragma unroll
      for (int qt = 0; qt < 2; ++qt)
        pf[qt] =
            *(const bf16x8*)&pbase[(qt * 16 + m16) * 36 + kk * 16 + quad * 4];
      lacc[0] = __builtin_amdgcn_mfma_f32_16x16x32_bf16(vone, pf[0], lacc[0],
                                                        0, 0, 0);
      lacc[1] = __builtin_amdgcn_mfma_f32_16x16x32_bf16(vone, pf[1], lacc[1],
                                                        0, 0, 0);
#pragma unroll
      for (int mtd = 0; mtd < 4; ++mtd) {
        const bf16x8 vf =
            *(const bf16x8*)&Vl[kk * 2048 + (mtd * 16 + m16) * 32 + quad * 8];
#pragma unroll
        for (int qt = 0; qt < 2; ++qt)
          oacc[qt][mtd] = __builtin_amdgcn_mfma_f32_16x16x32_bf16(
              vf, pf[qt], oacc[qt][mtd], 0, 0, 0);
      }
    }
    __syncthreads();
  }

#pragma unroll
  for (int qt = 0; qt < 2; ++qt) {
    // lacc rows are identical (ones-A); col = m16 matches this lane's q-row.
    const float linv = 1.0f / lacc[qt][0];
    const size_t obase =
        ((size_t)(b * 6144 + q0 + qt * 16 + m16)) * 1024 + h * 64;
#pragma unroll
    for (int mtd = 0; mtd < 4; ++mtd) {
      const int d0 = mtd * 16 + quad * 4;
      *(u32*)&O[obase + d0] =
          packbf(oacc[qt][mtd][0] * linv, oacc[qt][mtd][1] * linv);
      *(u32*)&O[obase + d0 + 2] =
          packbf(oacc[qt][mtd][2] * linv, oacc[qt][mtd][3] * linv);
    }
  }
}

// ===========================================================================
// Fallback GEMM (f32 operands converted in staging) — only if ws too small.
// ===========================================================================
template <bool A_BF16, bool OUT_F32, int VT, bool BIAS>
__global__ __launch_bounds__(256) void gemm_nt(
    const void* __restrict__ Ap, const float* __restrict__ W,
    void* __restrict__ Cp, const float* __restrict__ bias, int M, int N,
    int K, float scale) {
  __shared__ u16 As[128 * 40];
  __shared__ u16 Ws[128 * 40];
  const int tid = threadIdx.x;
  const int lane = tid & 63;
  const int wv = tid >> 6;
  const int wm = wv & 1, wn = wv >> 1;
  const int m16 = lane & 15, quad = lane >> 4;
  const int n0 = blockIdx.x * 128;
  const int m0 = blockIdx.y * 128;
  const int lr = tid >> 2;
  const int lc = (tid & 3) * 8;
  floatx4 acc[4][4];
#pragma unroll
  for (int i = 0; i < 4; ++i)
#pragma unroll
    for (int j = 0; j < 4; ++j) acc[i][j] = (floatx4)0.0f;
  const int KT = K >> 5;
  for (int kt = 0; kt < KT; ++kt) {
    const int k0 = kt << 5;
#pragma unroll
    for (int j = 0; j < 2; ++j) {
      const int r = lr + 64 * j;
      if (A_BF16) {
        *(uint4*)&As[r * 40 + lc] =
            *(const uint4*)&((const u16*)Ap)[(size_t)(m0 + r) * K + k0 + lc];
      } else {
        const float* Arow = (const float*)Ap + (size_t)(m0 + r) * K + k0 + lc;
        const float4 a0 = *(const float4*)Arow;
        const float4 a1 = *(const float4*)(Arow + 4);
        uint4 p;
        p.x = packbf(a0.x, a0.y); p.y = packbf(a0.z, a0.w);
        p.z = packbf(a1.x, a1.y); p.w = packbf(a1.z, a1.w);
        *(uint4*)&As[r * 40 + lc] = p;
      }
      const float* Wrow = W + (size_t)(n0 + r) * K + k0 + lc;
      const float4 w0 = *(const float4*)Wrow;
      const float4 w1 = *(const float4*)(Wrow + 4);
      uint4 q;
      q.x = packbf(w0.x, w0.y); q.y = packbf(w0.z, w0.w);
      q.z = packbf(w1.x, w1.y); q.w = packbf(w1.z, w1.w);
      *(uint4*)&Ws[r * 40 + lc] = q;
    }
    __syncthreads();
    bf16x8 af[4], bfr[4];
#pragma unroll
    for (int t = 0; t < 4; ++t) {
      af[t]  = *(const bf16x8*)&As[(wm * 64 + t * 16 + m16) * 40 + quad * 8];
      bfr[t] = *(const bf16x8*)&Ws[(wn * 64 + t * 16 + m16) * 40 + quad * 8];
    }
#pragma unroll
    for (int i = 0; i < 4; ++i)
#pragma unroll
      for (int j = 0; j < 4; ++j)
        acc[i][j] = __builtin_amdgcn_mfma_f32_16x16x32_bf16(af[i], bfr[j],
                                                            acc[i][j], 0, 0, 0);
    __syncthreads();
  }
#pragma unroll
  for (int j = 0; j < 4; ++j) {
    const int col = n0 + wn * 64 + j * 16 + m16;
    const float bv = BIAS ? bias[col] : 0.0f;
#pragma unroll
    for (int i = 0; i < 4; ++i)
#pragma unroll
      for (int r = 0; r < 4; ++r) {
        const int row = m0 + wm * 64 + i * 16 + quad * 4 + r;
        const float v = acc[i][j][r] * scale + bv;
        if (OUT_F32)
          ((float*)Cp)[(size_t)row * N + col] = v;
        else if (VT)
          ((u16*)Cp)[((size_t)((row >> 10) * 1024 + col)) * 1024 +
                     (row & 1023)] = f2bf(v);
        else
          ((u16*)Cp)[(size_t)row * N + col] = f2bf(v);
      }
  }
}

// ===========================================================================
extern "C" void kernel_launch(void* const* d_in, const int* in_sizes, int n_in,
                              void* d_out, int out_size, void* d_ws,
                              size_t ws_size, hipStream_t stream) {
  const float* x   = (const float*)d_in[0];
  const float* ctx = (const float*)d_in[1];
  const float* Wq  = (const float*)d_in[2];
  const float* Wk  = (const float*)d_in[3];
  const float* Wv  = (const float*)d_in[4];
  const float* Wo  = (const float*)d_in[5];
  const float* bo  = (const float*)d_in[6];
  float* out = (float*)d_out;
  const dim3 blk(256);
  const float CS = 0.18033688011112042f;  // 0.125 * log2(e)

  // Workspace layout (u16 units)
  u16* Qb   = (u16*)d_ws;            // 12582912
  u16* Kbuf = Qb + 12582912;         // 2097152
  u16* Vtb  = Kbuf + 2097152;        // 2097152
  u16* Obx  = Vtb + 2097152;         // 12582912 (xb before attn, Ob after)
  u16* ctxb = Obx + 12582912;        // 2097152
  u16* wqb  = ctxb + 2097152;        // 1048576
  u16* wkb  = wqb + 1048576;
  u16* wvb  = wkb + 1048576;
  u16* wob  = wvb + 1048576;
  const size_t need = (size_t)(wob + 1048576 - Qb) * sizeof(u16);  // 71.3 MB

  if (ws_size >= need) {
    cvt_all<<<18432, blk, 0, stream>>>(x, ctx, Wq, Wk, Wv, Wo, Obx, ctxb, wqb,
                                       wkb, wvb, wob);
    gemm_qkv<<<dim3(8, 128), blk, 0, stream>>>(Obx, ctxb, wqb, wkb, wvb, Qb,
                                               Kbuf, Vtb);
    attn_flash<<<dim3(48, 16, 2), blk, 0, stream>>>(Qb, Kbuf, Vtb, Obx);
    gemm_out<<<dim3(8, 96), blk, 0, stream>>>(Obx, wob, out, bo);
  } else {
    gemm_nt<false, false, 0, false><<<dim3(8, 96), blk, 0, stream>>>(
        x, Wq, Qb, nullptr, 12288, 1024, 1024, CS);
    gemm_nt<false, false, 0, false><<<dim3(8, 16), blk, 0, stream>>>(
        ctx, Wk, Kbuf, nullptr, 2048, 1024, 1024, 1.0f);
    gemm_nt<false, false, 1, false><<<dim3(8, 16), blk, 0, stream>>>(
        ctx, Wv, Vtb, nullptr, 2048, 1024, 1024, 1.0f);
    attn_flash<<<dim3(48, 16, 2), blk, 0, stream>>>(Qb, Kbuf, Vtb, Obx);
    gemm_nt<true, true, 0, true><<<dim3(8, 96), blk, 0, stream>>>(
        Obx, Wo, out, bo, 12288, 1024, 1024, 1.0f);
  }
}

// Round 7
// 257.087 us; speedup vs baseline: 1.1637x; 1.1227x over previous
//
#include <hip/hip_runtime.h>

typedef short bf16x8 __attribute__((ext_vector_type(8)));
typedef float floatx4 __attribute__((ext_vector_type(4)));
typedef unsigned short u16;
typedef unsigned int u32;

__device__ __forceinline__ u16 f2bf(float f) {
  u32 u = __float_as_uint(f);
  u += 0x7FFF + ((u >> 16) & 1);   // round-to-nearest-even
  return (u16)(u >> 16);
}
__device__ __forceinline__ u32 packbf(float a, float b) {
  return (u32)f2bf(a) | ((u32)f2bf(b) << 16);
}
// One-instruction RTZ bf16 pair pack: D = {hi16(b), hi16(a)} via v_perm_b32.
__device__ __forceinline__ u32 permpack(u32 a_bits, u32 b_bits) {
  return __builtin_amdgcn_perm(b_bits, a_bits, 0x07060302u);
}

// Raw v_exp_f32: flush-to-zero on underflow (softmax-safe).
__device__ __forceinline__ float ex2(float x) {
#if __has_builtin(__builtin_amdgcn_exp2f)
  return __builtin_amdgcn_exp2f(x);
#else
  float r;
  asm("v_exp_f32 %0, %1" : "=v"(r) : "v"(x));
  return r;
#endif
}

// Async global->LDS DMA, 16 B/lane. LDS dest wave-uniform; lane i lands at
// ldsbase + i*16 (m97/m104 semantics).
__device__ __forceinline__ void gload_lds16(const u16* g, u16* l) {
  __builtin_amdgcn_global_load_lds(
      (const __attribute__((address_space(1))) void*)(const void*)g,
      (__attribute__((address_space(3))) void*)(void*)l, 16, 0, 0);
}

// XCD-aware bijective block swizzle (T1, m204 form; requires nwg % 8 == 0).
__device__ __forceinline__ int xcd_swz(int disp, int nwg) {
  const int q = nwg >> 3;
  return (disp & 7) * q + (disp >> 3);
}

// ===========================================================================
// bf16 GEMM (NT) building blocks: 128x128 tile, 4 waves (2x2 of 64x64).
// Mainloop uses BK=64 as TWO [128][32] sub-tiles per barrier pair (same LDS
// row stride / DMA idiom / FP sum order as the proven BK=32 loop — only the
// barrier count halves, amortizing the fixed per-step stage-drain overhead
// that dominates at this shape; 3 pipelining attempts all regressed, see
// R2/R4/R6). LDS 2x16KB -> 4 blocks/CU. K fixed at 1024 (16 steps).
// ===========================================================================
__device__ __forceinline__ void bb_frags(const u16* As, const u16* Ws, int wm,
                                         int wn, int m16, int quad,
                                         bf16x8 af[4], bf16x8 bfr[4]) {
#pragma unroll
  for (int t = 0; t < 4; ++t) {
    af[t]  = *(const bf16x8*)&As[(wm * 64 + t * 16 + m16) * 32 + quad * 8];
    bfr[t] = *(const bf16x8*)&Ws[(wn * 64 + t * 16 + m16) * 32 + quad * 8];
  }
}

__device__ __forceinline__ void bb_mfma(const bf16x8 af[4], const bf16x8 bfr[4],
                                        floatx4 acc[4][4]) {
#pragma unroll
  for (int i = 0; i < 4; ++i)
#pragma unroll
    for (int j = 0; j < 4; ++j)
      acc[i][j] = __builtin_amdgcn_mfma_f32_16x16x32_bf16(af[i], bfr[j],
                                                          acc[i][j], 0, 0, 0);
}

__device__ __forceinline__ void bb_mainloop64(const u16* __restrict__ A,
                                              const u16* __restrict__ W,
                                              u16* As, u16* Ws, int m0, int n0,
                                              floatx4 acc[4][4]) {
  const int tid = threadIdx.x, lane = tid & 63, w = tid >> 6;
  const int wm = w & 1, wn = w >> 1;
  const int m16 = lane & 15, quad = lane >> 4;
  const int lr = lane >> 2;        // 16 rows per DMA sweep
  const int sc = (lane & 3) * 8;   // 8 bf16 = 16 B per lane

  const u16* Ag = A + (size_t)(m0 + w * 32 + lr) * 1024 + sc;
  const u16* Wg = W + (size_t)(n0 + w * 32 + lr) * 1024 + sc;
  u16* const Asl = &As[(w * 32) * 32];
  u16* const Wsl = &Ws[(w * 32) * 32];

#pragma unroll
  for (int i = 0; i < 4; ++i)
#pragma unroll
    for (int j = 0; j < 4; ++j) acc[i][j] = (floatx4)0.0f;

  for (int kt = 0; kt < 16; ++kt) {
    // k-lo sub-tile -> [0,4096), k-hi -> [4096,8192) (u16 units)
    gload_lds16(Ag, Asl);
    gload_lds16(Ag + 16 * 1024, Asl + 512);
    gload_lds16(Ag + 32, Asl + 4096);
    gload_lds16(Ag + 32 + 16 * 1024, Asl + 4096 + 512);
    gload_lds16(Wg, Wsl);
    gload_lds16(Wg + 16 * 1024, Wsl + 512);
    gload_lds16(Wg + 32, Wsl + 4096);
    gload_lds16(Wg + 32 + 16 * 1024, Wsl + 4096 + 512);
    Ag += 64;
    Wg += 64;
    __syncthreads();
    bf16x8 af[4], bfr[4];
    bb_frags(As, Ws, wm, wn, m16, quad, af, bfr);
    bb_mfma(af, bfr, acc);
    bb_frags(As + 4096, Ws + 4096, wm, wn, m16, quad, af, bfr);
    bb_mfma(af, bfr, acc);
    __syncthreads();
  }
}

// ===========================================================================
// Merged Q/K/V projection: 1024 work ids, XCD-swizzled. y<96: Q (scaled by
// 0.125*log2e); [96,112): K; [112,128): V (transposed store
// Vt[b][h*64+d][s], packed 8B stores). Branches are block-uniform.
// ===========================================================================
__global__ __launch_bounds__(256, 4) void gemm_qkv(
    const u16* __restrict__ xb, const u16* __restrict__ ctxb,
    const u16* __restrict__ wqb, const u16* __restrict__ wkb,
    const u16* __restrict__ wvb, u16* __restrict__ Qb, u16* __restrict__ Kbuf,
    u16* __restrict__ Vtb) {
  __shared__ u16 As[128 * 64];
  __shared__ u16 Ws[128 * 64];
  const int lane = threadIdx.x & 63, w = threadIdx.x >> 6;
  const int wm = w & 1, wn = w >> 1;
  const int m16 = lane & 15, quad = lane >> 4;
  const int disp = blockIdx.y * 8 + blockIdx.x;
  const int work = xcd_swz(disp, 1024);
  const int y = work >> 3;
  const int n0 = (work & 7) * 128;
  const u16 *A, *W;
  int m0, mode;
  if (y < 96)       { A = xb;   W = wqb; m0 = y * 128;         mode = 0; }
  else if (y < 112) { A = ctxb; W = wkb; m0 = (y - 96) * 128;  mode = 1; }
  else              { A = ctxb; W = wvb; m0 = (y - 112) * 128; mode = 2; }
  floatx4 acc[4][4];
  bb_mainloop64(A, W, As, Ws, m0, n0, acc);
  const float cs = (mode == 0) ? 0.18033688011112042f : 1.0f;
#pragma unroll
  for (int j = 0; j < 4; ++j) {
    const int col = n0 + wn * 64 + j * 16 + m16;
#pragma unroll
    for (int i = 0; i < 4; ++i) {
      if (mode == 2) {
        // Vt: r-values are address-consecutive -> one 8B packed store.
        const int row0 = m0 + wm * 64 + i * 16 + quad * 4;
        uint2 pv;
        pv.x = packbf(acc[i][j][0], acc[i][j][1]);
        pv.y = packbf(acc[i][j][2], acc[i][j][3]);
        *(uint2*)&Vtb[((size_t)((row0 >> 10) * 1024 + col)) * 1024 +
                      (row0 & 1023)] = pv;
      } else {
#pragma unroll
        for (int r = 0; r < 4; ++r) {
          const int row = m0 + wm * 64 + i * 16 + quad * 4 + r;
          const u16 v = f2bf(acc[i][j][r] * cs);
          if (mode == 0)
            Qb[(size_t)row * 1024 + col] = v;
          else
            Kbuf[(size_t)row * 1024 + col] = v;
        }
      }
    }
  }
}

// Output projection: bf16 A/W -> f32 out + bias. XCD-swizzled (768 blocks).
__global__ __launch_bounds__(256, 4) void gemm_out(const u16* __restrict__ A,
                                                   const u16* __restrict__ W,
                                                   float* __restrict__ C,
                                                   const float* __restrict__ bias) {
  __shared__ u16 As[128 * 64];
  __shared__ u16 Ws[128 * 64];
  const int lane = threadIdx.x & 63, w = threadIdx.x >> 6;
  const int wm = w & 1, wn = w >> 1;
  const int m16 = lane & 15, quad = lane >> 4;
  const int disp = blockIdx.y * 8 + blockIdx.x;
  const int work = xcd_swz(disp, 768);
  const int n0 = (work & 7) * 128, m0 = (work >> 3) * 128;
  floatx4 acc[4][4];
  bb_mainloop64(A, W, As, Ws, m0, n0, acc);
#pragma unroll
  for (int j = 0; j < 4; ++j) {
    const int col = n0 + wn * 64 + j * 16 + m16;
    const float bv = bias[col];
#pragma unroll
    for (int i = 0; i < 4; ++i)
#pragma unroll
      for (int r = 0; r < 4; ++r) {
        const int row = m0 + wm * 64 + i * 16 + quad * 4 + r;
        C[(size_t)row * 1024 + col] = acc[i][j][r] + bv;
      }
  }
}

// ===========================================================================
// f32 -> bf16 conversion of all operands.
// ===========================================================================
__global__ __launch_bounds__(256) void cvt_all(
    const float* __restrict__ x, const float* __restrict__ ctx,
    const float* __restrict__ wq, const float* __restrict__ wk,
    const float* __restrict__ wv, const float* __restrict__ wo,
    u16* __restrict__ xb, u16* __restrict__ ctxb, u16* __restrict__ wqb,
    u16* __restrict__ wkb, u16* __restrict__ wvb, u16* __restrict__ wob) {
  const u32 i = blockIdx.x * 256 + threadIdx.x;
  const float* s;
  u16* d;
  u32 o;
  if (i < 3145728u)      { s = x;   d = xb;   o = i; }
  else if (i < 3670016u) { s = ctx; d = ctxb; o = i - 3145728u; }
  else if (i < 3932160u) { s = wq;  d = wqb;  o = i - 3670016u; }
  else if (i < 4194304u) { s = wk;  d = wkb;  o = i - 3932160u; }
  else if (i < 4456448u) { s = wv;  d = wvb;  o = i - 4194304u; }
  else                   { s = wo;  d = wob;  o = i - 4456448u; }
  const float4 v = ((const float4*)s)[o];
  uint2 p;
  p.x = packbf(v.x, v.y);
  p.y = packbf(v.z, v.w);
  ((uint2*)d)[o] = p;
}

// ===========================================================================
// Flash attention, VALU-trimmed (raw v_exp_f32; MFMA-pipe row-sum), with
// XCD swizzle: each XCD owns 4 contiguous (b,h) pairs -> K/V working set
// 1 MB << 4 MB L2. 64-key tiles, LDS 34.8 KB -> 4 blocks/CU.
// ===========================================================================
__global__ __launch_bounds__(256, 4) void attn_flash(
    const u16* __restrict__ Q, const u16* __restrict__ Kb,
    const u16* __restrict__ Vt, u16* __restrict__ O) {
  __shared__ u16 Kl[2 * 64 * 32];   // [ks][s 64][d 32]
  __shared__ u16 Vl[2 * 64 * 32];   // [sub][d 64][s 32]
  __shared__ u32 Pl[4 * 32 * 36];   // per-wave [q 32][36 dw] (32 payload)
  const int tid = threadIdx.x, lane = tid & 63, w = tid >> 6;
  const int m16 = lane & 15, quad = lane >> 4;
  const int disp =
      blockIdx.x + 48 * (blockIdx.y + 16 * blockIdx.z);  // [0,1536)
  const int work = xcd_swz(disp, 1536);
  const int qx = work % 48;
  const int bh = work / 48;          // [0,32)
  const int h = bh & 15, b = bh >> 4;
  const int q0 = qx * 128 + w * 32;
  u32* const pbase = &Pl[w * 32 * 36];

  // Q fragments (B-operand), already scaled in projection.
  bf16x8 aq[2][2];
#pragma unroll
  for (int qt = 0; qt < 2; ++qt)
#pragma unroll
    for (int ks = 0; ks < 2; ++ks)
      aq[qt][ks] =
          *(const bf16x8*)&Q[((size_t)(b * 6144 + q0 + qt * 16 + m16)) * 1024 +
                             h * 64 + ks * 32 + quad * 8];

  // DMA assignment: wave w -> ks/sub = w&1, row-half = w>>1.
  const int wk = w & 1, wh = w >> 1;
  const u16* kg = Kb + ((size_t)(b * 1024 + wh * 32 + (lane >> 2))) * 1024 +
                  h * 64 + wk * 32 + (lane & 3) * 8;
  const u16* vg = Vt + ((size_t)(b * 16 + h)) * 65536 +
                  (size_t)(wh * 32 + (lane >> 2)) * 1024 + wk * 32 +
                  (lane & 3) * 8;
  u16* const klb = &Kl[wk * 2048 + wh * 1024];
  u16* const vlb = &Vl[wk * 2048 + wh * 1024];

  // All-ones A-operand for the row-sum MFMA.
  bf16x8 vone;
#pragma unroll
  for (int e = 0; e < 8; ++e) vone[e] = (short)0x3F80;

  floatx4 oacc[2][4];
#pragma unroll
  for (int qt = 0; qt < 2; ++qt)
#pragma unroll
    for (int mtd = 0; mtd < 4; ++mtd) oacc[qt][mtd] = (floatx4)0.0f;
  floatx4 lacc[2];
  lacc[0] = (floatx4)0.0f;
  lacc[1] = (floatx4)0.0f;

#pragma unroll 1
  for (int kt = 0; kt < 16; ++kt) {
    // stage K[64s][64d] + Vt[64d][64s] (16 KB total, 4 DMA per wave)
    gload_lds16(kg, klb);
    gload_lds16(kg + 16 * 1024, klb + 512);
    gload_lds16(vg, vlb);
    gload_lds16(vg + 16 * 1024, vlb + 512);
    kg += 64 * 1024;
    vg += 64;
    __syncthreads();

    // Phase A: S^T[s 64][q 32] = K @ Q^T (exp2 domain)
    floatx4 sst[2][4];
#pragma unroll
    for (int mt = 0; mt < 4; ++mt) {
      const int row = mt * 16 + m16;
      const bf16x8 kf0 = *(const bf16x8*)&Kl[row * 32 + quad * 8];
      const bf16x8 kf1 = *(const bf16x8*)&Kl[2048 + row * 32 + quad * 8];
#pragma unroll
      for (int qt = 0; qt < 2; ++qt) {
        floatx4 t = (floatx4)0.0f;
        t = __builtin_amdgcn_mfma_f32_16x16x32_bf16(kf0, aq[qt][0], t, 0, 0, 0);
        sst[qt][mt] =
            __builtin_amdgcn_mfma_f32_16x16x32_bf16(kf1, aq[qt][1], t, 0, 0, 0);
      }
    }
    // Softmax numerators: p = exp2(s), raw v_exp_f32; RTZ-pack via v_perm.
#pragma unroll
    for (int qt = 0; qt < 2; ++qt) {
      u32* const prow = &pbase[(qt * 16 + m16) * 36 + quad * 2];
#pragma unroll
      for (int mt = 0; mt < 4; ++mt) {
        const u32 b0 = __float_as_uint(ex2(sst[qt][mt][0]));
        const u32 b1 = __float_as_uint(ex2(sst[qt][mt][1]));
        const u32 b2 = __float_as_uint(ex2(sst[qt][mt][2]));
        const u32 b3 = __float_as_uint(ex2(sst[qt][mt][3]));
        uint2 pk;
        pk.x = permpack(b0, b1);
        pk.y = permpack(b2, b3);
        *(uint2*)&prow[mt * 8] = pk;
      }
    }
    // Phase B: O^T += Vt @ P^T; ones-MFMA accumulates l = sum_k p.
#pragma unroll
    for (int kk = 0; kk < 2; ++kk) {
      bf16x8 pf[2];
#pragma unroll
      for (int qt = 0; qt < 2; ++qt)
        pf[qt] =
            *(const bf16x8*)&pbase[(qt * 16 + m16) * 36 + kk * 16 + quad * 4];
      lacc[0] = __builtin_amdgcn_mfma_f32_16x16x32_bf16(vone, pf[0], lacc[0],
                                                        0, 0, 0);
      lacc[1] = __builtin_amdgcn_mfma_f32_16x16x32_bf16(vone, pf[1], lacc[1],
                                                        0, 0, 0);
#pragma unroll
      for (int mtd = 0; mtd < 4; ++mtd) {
        const bf16x8 vf =
            *(const bf16x8*)&Vl[kk * 2048 + (mtd * 16 + m16) * 32 + quad * 8];
#pragma unroll
        for (int qt = 0; qt < 2; ++qt)
          oacc[qt][mtd] = __builtin_amdgcn_mfma_f32_16x16x32_bf16(
              vf, pf[qt], oacc[qt][mtd], 0, 0, 0);
      }
    }
    __syncthreads();
  }

#pragma unroll
  for (int qt = 0; qt < 2; ++qt) {
    // lacc rows are identical (ones-A); col = m16 matches this lane's q-row.
    const float linv = 1.0f / lacc[qt][0];
    const size_t obase =
        ((size_t)(b * 6144 + q0 + qt * 16 + m16)) * 1024 + h * 64;
#pragma unroll
    for (int mtd = 0; mtd < 4; ++mtd) {
      const int d0 = mtd * 16 + quad * 4;
      *(u32*)&O[obase + d0] =
          packbf(oacc[qt][mtd][0] * linv, oacc[qt][mtd][1] * linv);
      *(u32*)&O[obase + d0 + 2] =
          packbf(oacc[qt][mtd][2] * linv, oacc[qt][mtd][3] * linv);
    }
  }
}

// ===========================================================================
// Fallback GEMM (f32 operands converted in staging) — only if ws too small.
// ===========================================================================
template <bool A_BF16, bool OUT_F32, int VT, bool BIAS>
__global__ __launch_bounds__(256) void gemm_nt(
    const void* __restrict__ Ap, const float* __restrict__ W,
    void* __restrict__ Cp, const float* __restrict__ bias, int M, int N,
    int K, float scale) {
  __shared__ u16 As[128 * 40];
  __shared__ u16 Ws[128 * 40];
  const int tid = threadIdx.x;
  const int lane = tid & 63;
  const int wv = tid >> 6;
  const int wm = wv & 1, wn = wv >> 1;
  const int m16 = lane & 15, quad = lane >> 4;
  const int n0 = blockIdx.x * 128;
  const int m0 = blockIdx.y * 128;
  const int lr = tid >> 2;
  const int lc = (tid & 3) * 8;
  floatx4 acc[4][4];
#pragma unroll
  for (int i = 0; i < 4; ++i)
#pragma unroll
    for (int j = 0; j < 4; ++j) acc[i][j] = (floatx4)0.0f;
  const int KT = K >> 5;
  for (int kt = 0; kt < KT; ++kt) {
    const int k0 = kt << 5;
#pragma unroll
    for (int j = 0; j < 2; ++j) {
      const int r = lr + 64 * j;
      if (A_BF16) {
        *(uint4*)&As[r * 40 + lc] =
            *(const uint4*)&((const u16*)Ap)[(size_t)(m0 + r) * K + k0 + lc];
      } else {
        const float* Arow = (const float*)Ap + (size_t)(m0 + r) * K + k0 + lc;
        const float4 a0 = *(const float4*)Arow;
        const float4 a1 = *(const float4*)(Arow + 4);
        uint4 p;
        p.x = packbf(a0.x, a0.y); p.y = packbf(a0.z, a0.w);
        p.z = packbf(a1.x, a1.y); p.w = packbf(a1.z, a1.w);
        *(uint4*)&As[r * 40 + lc] = p;
      }
      const float* Wrow = W + (size_t)(n0 + r) * K + k0 + lc;
      const float4 w0 = *(const float4*)Wrow;
      const float4 w1 = *(const float4*)(Wrow + 4);
      uint4 q;
      q.x = packbf(w0.x, w0.y); q.y = packbf(w0.z, w0.w);
      q.z = packbf(w1.x, w1.y); q.w = packbf(w1.z, w1.w);
      *(uint4*)&Ws[r * 40 + lc] = q;
    }
    __syncthreads();
    bf16x8 af[4], bfr[4];
#pragma unroll
    for (int t = 0; t < 4; ++t) {
      af[t]  = *(const bf16x8*)&As[(wm * 64 + t * 16 + m16) * 40 + quad * 8];
      bfr[t] = *(const bf16x8*)&Ws[(wn * 64 + t * 16 + m16) * 40 + quad * 8];
    }
#pragma unroll
    for (int i = 0; i < 4; ++i)
#pragma unroll
      for (int j = 0; j < 4; ++j)
        acc[i][j] = __builtin_amdgcn_mfma_f32_16x16x32_bf16(af[i], bfr[j],
                                                            acc[i][j], 0, 0, 0);
    __syncthreads();
  }
#pragma unroll
  for (int j = 0; j < 4; ++j) {
    const int col = n0 + wn * 64 + j * 16 + m16;
    const float bv = BIAS ? bias[col] : 0.0f;
#pragma unroll
    for (int i = 0; i < 4; ++i)
#pragma unroll
      for (int r = 0; r < 4; ++r) {
        const int row = m0 + wm * 64 + i * 16 + quad * 4 + r;
        const float v = acc[i][j][r] * scale + bv;
        if (OUT_F32)
          ((float*)Cp)[(size_t)row * N + col] = v;
        else if (VT)
          ((u16*)Cp)[((size_t)((row >> 10) * 1024 + col)) * 1024 +
                     (row & 1023)] = f2bf(v);
        else
          ((u16*)Cp)[(size_t)row * N + col] = f2bf(v);
      }
  }
}

// ===========================================================================
extern "C" void kernel_launch(void* const* d_in, const int* in_sizes, int n_in,
                              void* d_out, int out_size, void* d_ws,
                              size_t ws_size, hipStream_t stream) {
  const float* x   = (const float*)d_in[0];
  const float* ctx = (const float*)d_in[1];
  const float* Wq  = (const float*)d_in[2];
  const float* Wk  = (const float*)d_in[3];
  const float* Wv  = (const float*)d_in[4];
  const float* Wo  = (const float*)d_in[5];
  const float* bo  = (const float*)d_in[6];
  float* out = (float*)d_out;
  const dim3 blk(256);
  const float CS = 0.18033688011112042f;  // 0.125 * log2(e)

  // Workspace layout (u16 units)
  u16* Qb   = (u16*)d_ws;            // 12582912
  u16* Kbuf = Qb + 12582912;         // 2097152
  u16* Vtb  = Kbuf + 2097152;        // 2097152
  u16* Obx  = Vtb + 2097152;         // 12582912 (xb before attn, Ob after)
  u16* ctxb = Obx + 12582912;        // 2097152
  u16* wqb  = ctxb + 2097152;        // 1048576
  u16* wkb  = wqb + 1048576;
  u16* wvb  = wkb + 1048576;
  u16* wob  = wvb + 1048576;
  const size_t need = (size_t)(wob + 1048576 - Qb) * sizeof(u16);  // 71.3 MB

  if (ws_size >= need) {
    cvt_all<<<18432, blk, 0, stream>>>(x, ctx, Wq, Wk, Wv, Wo, Obx, ctxb, wqb,
                                       wkb, wvb, wob);
    gemm_qkv<<<dim3(8, 128), blk, 0, stream>>>(Obx, ctxb, wqb, wkb, wvb, Qb,
                                               Kbuf, Vtb);
    attn_flash<<<dim3(48, 16, 2), blk, 0, stream>>>(Qb, Kbuf, Vtb, Obx);
    gemm_out<<<dim3(8, 96), blk, 0, stream>>>(Obx, wob, out, bo);
  } else {
    gemm_nt<false, false, 0, false><<<dim3(8, 96), blk, 0, stream>>>(
        x, Wq, Qb, nullptr, 12288, 1024, 1024, CS);
    gemm_nt<false, false, 0, false><<<dim3(8, 16), blk, 0, stream>>>(
        ctx, Wk, Kbuf, nullptr, 2048, 1024, 1024, 1.0f);
    gemm_nt<false, false, 1, false><<<dim3(8, 16), blk, 0, stream>>>(
        ctx, Wv, Vtb, nullptr, 2048, 1024, 1024, 1.0f);
    attn_flash<<<dim3(48, 16, 2), blk, 0, stream>>>(Qb, Kbuf, Vtb, Obx);
    gemm_nt<true, true, 0, true><<<dim3(8, 96), blk, 0, stream>>>(
        Obx, Wo, out, bo, 12288, 1024, 1024, 1.0f);
  }
}